// Round 10
// baseline (210.071 us; speedup 1.0000x reference)
//
#include <hip/hip_runtime.h>

// ---------------------------------------------------------------------------
// 2-layer GCN + mean-pool + MLP head.
// R4-R7: bf16 MFMA GEMMs, bf16 Hs, launch diet, agg MLP tuning.
// R9: agg1 fused into gemm2 A-staging; pool fused into agg2. 9 dispatches.
// R10: gemm2_agg single-pass full-row gather (W2t fully LDS-resident, one
//      barrier, 2x in-flight gather bytes); nontemporal csr loads;
//      agg2_pool unroll-8 tier.
// ---------------------------------------------------------------------------

#define HID 128

typedef __attribute__((ext_vector_type(8))) short bf16x8;
typedef __attribute__((ext_vector_type(4))) short bf16x4;
typedef __attribute__((ext_vector_type(4))) float f32x4;

static __device__ __forceinline__ short f2bf(float f) {
  union { float f; unsigned u; } v; v.f = f;
  unsigned r = v.u + 0x7fff + ((v.u >> 16) & 1);  // RNE
  return (short)(r >> 16);
}
static __device__ __forceinline__ float bf2f(short s) {
  union { unsigned u; float f; } v;
  v.u = ((unsigned)(unsigned short)s) << 16;
  return v.f;
}

// --- W1/W2 fp32 -> Wt bf16 (transpose + convert) + zero deg (fused) ---
__global__ __launch_bounds__(256) void prep_w_k(const float* __restrict__ W1,
                                                short* __restrict__ W1t,
                                                const float* __restrict__ W2,
                                                short* __restrict__ W2t,
                                                int* __restrict__ deg, int N) {
  int idx = blockIdx.x * 256 + threadIdx.x;
  if (idx < 384 * HID) {
    int k = idx >> 7;
    int c = idx & 127;
    W1t[(size_t)c * 384 + k] = f2bf(W1[idx]);
  } else if (idx < 384 * HID + HID * HID) {
    int j = idx - 384 * HID;
    int k = j >> 7;
    int c = j & 127;
    W2t[(size_t)c * HID + k] = f2bf(W2[j]);
  }
  if (idx < N) deg[idx] = 0;
}

__global__ __launch_bounds__(256) void hist_k(const int* __restrict__ dst,
                                              int* __restrict__ cnt, int E) {
  int i = blockIdx.x * 256 + threadIdx.x;
  if (i < E) atomicAdd(&cnt[dst[i]], 1);
}

// per-256-chunk sums of deg + dinv computation (fused)
__global__ __launch_bounds__(256) void scan_bsum(const int* __restrict__ cnt,
                                                 int* __restrict__ bsum,
                                                 float* __restrict__ dinv, int n) {
  __shared__ int sm[256];
  int i = blockIdx.x * 256 + threadIdx.x;
  int v = (i < n) ? cnt[i] : 0;
  if (i < n) dinv[i] = rsqrtf((float)(v + 1));  // +1 self-loop
  sm[threadIdx.x] = v;
  __syncthreads();
  for (int off = 128; off > 0; off >>= 1) {
    if (threadIdx.x < off) sm[threadIdx.x] += sm[threadIdx.x + off];
    __syncthreads();
  }
  if (threadIdx.x == 0) bsum[blockIdx.x] = sm[0];
}

// offsets: inline exclusive scan of bsum (nb<=256) + per-chunk scan
//          + cur=0 + sums=0 (fused zeroing)
__global__ __launch_bounds__(256) void scan_offsets(const int* __restrict__ cnt,
                                                    const int* __restrict__ bsum,
                                                    int* __restrict__ offs,
                                                    int* __restrict__ cur,
                                                    float* __restrict__ sums,
                                                    int nsum, int n, int nb) {
  __shared__ int sm[256];
  int t = threadIdx.x;
  int bid = blockIdx.x;
  int zi = bid * 256 + t;
  if (zi < nsum) sums[zi] = 0.f;
  // pass 1: inclusive scan of bsum in LDS
  int bv = (t < nb) ? bsum[t] : 0;
  sm[t] = bv;
  __syncthreads();
  for (int off = 1; off < 256; off <<= 1) {
    int add = (t >= off) ? sm[t - off] : 0;
    __syncthreads();
    sm[t] += add;
    __syncthreads();
  }
  int base = (bid > 0) ? sm[bid - 1] : 0;  // exclusive prefix for this block
  __syncthreads();
  // pass 2: scan this block's 256-deg chunk
  int i = bid * 256 + t;
  int v = (i < n) ? cnt[i] : 0;
  sm[t] = v;
  __syncthreads();
  for (int off = 1; off < 256; off <<= 1) {
    int add = (t >= off) ? sm[t - off] : 0;
    __syncthreads();
    sm[t] += add;
    __syncthreads();
  }
  if (i < n) {
    offs[i] = base + sm[t] - v;
    cur[i] = 0;
  }
  if (i == n - 1) offs[n] = base + sm[t];  // total
}

__global__ __launch_bounds__(256) void fill_k(const int* __restrict__ src,
                                              const int* __restrict__ dst,
                                              const int* __restrict__ offs,
                                              int* __restrict__ cur,
                                              int* __restrict__ csr, int E) {
  int i = blockIdx.x * 256 + threadIdx.x;
  if (i >= E) return;
  int d = dst[i];
  int p = offs[d] + atomicAdd(&cur[d], 1);
  csr[p] = src[i];
}

// --- GEMM1: Hs1[M][128] = bf16( (node_x[M][384] @ W1t^T) * dinv[row] ) ---
// 64x128 tile, 4 waves (2x2 of 32x64), BK=64, mfma_f32_16x16x32_bf16.
__global__ __launch_bounds__(256) void mfma_gemm1_k(const float* __restrict__ Af,
                                                    const short* __restrict__ Wt,
                                                    const float* __restrict__ scale,
                                                    short* __restrict__ C, int M) {
  constexpr int K = 384;
  constexpr int BK = 64;
  constexpr int ROWE = BK + 8;  // 72 shorts = 144B rows (16B aligned)
  __shared__ short As[64 * ROWE];
  __shared__ short Bs[128 * ROWE];
  __shared__ float dln[64];

  const int tid = threadIdx.x;
  const int wave = tid >> 6;
  const int lane = tid & 63;
  const int l15 = lane & 15;
  const int lk = lane >> 4;          // k-group 0..3
  const int mh = (wave >> 1) * 32;   // wave row offset in tile
  const int nh = (wave & 1) * 64;    // wave col offset
  const int row0 = blockIdx.x * 64;

  if (tid < 64) {
    int r = row0 + tid;
    dln[tid] = (r < M) ? scale[r] : 0.f;
  }

  f32x4 acc[2][4] = {};

  for (int k0 = 0; k0 < K; k0 += BK) {
    __syncthreads();  // previous iter's LDS reads done before overwrite
#pragma unroll
    for (int it = 0; it < 4; ++it) {
      int f = tid + it * 256;
      int r = f >> 4;
      int kc = (f & 15) << 2;
      int gr = row0 + r;
      float4 v = make_float4(0.f, 0.f, 0.f, 0.f);
      if (gr < M) v = *(const float4*)&Af[(size_t)gr * K + k0 + kc];
      bf16x4 s;
      s[0] = f2bf(v.x); s[1] = f2bf(v.y); s[2] = f2bf(v.z); s[3] = f2bf(v.w);
      *(bf16x4*)&As[r * ROWE + kc] = s;
    }
#pragma unroll
    for (int it = 0; it < 4; ++it) {
      int f = tid + it * 256;
      int r = f >> 3;
      int kc = (f & 7) << 3;
      *(bf16x8*)&Bs[r * ROWE + kc] =
          *(const bf16x8*)&Wt[(size_t)r * K + k0 + kc];
    }
    __syncthreads();
#pragma unroll
    for (int ks = 0; ks < 2; ++ks) {
      bf16x8 af[2], bfr[4];
#pragma unroll
      for (int mf = 0; mf < 2; ++mf)
        af[mf] = *(const bf16x8*)&As[(mh + mf * 16 + l15) * ROWE + ks * 32 + lk * 8];
#pragma unroll
      for (int nf = 0; nf < 4; ++nf)
        bfr[nf] = *(const bf16x8*)&Bs[(nh + nf * 16 + l15) * ROWE + ks * 32 + lk * 8];
#pragma unroll
      for (int mf = 0; mf < 2; ++mf)
#pragma unroll
        for (int nf = 0; nf < 4; ++nf)
          acc[mf][nf] = __builtin_amdgcn_mfma_f32_16x16x32_bf16(
              af[mf], bfr[nf], acc[mf][nf], 0, 0, 0);
    }
  }
  // epilogue: C/D layout col=lane&15, row=(lane>>4)*4+reg
#pragma unroll
  for (int mf = 0; mf < 2; ++mf) {
#pragma unroll
    for (int r = 0; r < 4; ++r) {
      int lr = mh + mf * 16 + lk * 4 + r;
      int gr = row0 + lr;
      if (gr >= M) continue;
      float s = dln[lr];
#pragma unroll
      for (int nf = 0; nf < 4; ++nf)
        C[(size_t)gr * HID + nh + nf * 16 + l15] = f2bf(acc[mf][nf][r] * s);
    }
  }
}

// --- GEMM2 with fused AGG1, single-pass:
//   g1[v][:] = relu(dinv[v]*(Hs1[v]+sum_in Hs1[u]) + b1) gathered ONCE
//   (full 128-col rows, 4 threads/row x 32 cols, 4 loads/edge, unroll x4),
//   W2t fully LDS-resident; ONE barrier; 4 MFMA k-steps.
__global__ __launch_bounds__(256) void gemm2_agg_k(const short* __restrict__ Hs,
                                                   const int* __restrict__ offs,
                                                   const int* __restrict__ csr,
                                                   const float* __restrict__ dinv,
                                                   const float* __restrict__ b1,
                                                   const short* __restrict__ Wt,
                                                   short* __restrict__ C, int M) {
  constexpr int K = 128;
  constexpr int ROWE = K + 8;  // 136 shorts = 272B rows (16B-aligned units)
  __shared__ short As[64 * ROWE];
  __shared__ short Bs[128 * ROWE];
  __shared__ float dln[64];

  const int tid = threadIdx.x;
  const int wave = tid >> 6;
  const int lane = tid & 63;
  const int l15 = lane & 15;
  const int lk = lane >> 4;
  const int mh = (wave >> 1) * 32;
  const int nh = (wave & 1) * 64;
  const int row0 = blockIdx.x * 64;

  if (tid < 64) {
    int r = row0 + tid;
    dln[tid] = (r < M) ? dinv[r] : 0.f;
  }

  // stage ALL of W2t: 128 rows x 128 cols, 8 x bf16x8 per thread
#pragma unroll
  for (int it = 0; it < 8; ++it) {
    int f = tid + it * 256;          // 0..2047
    int r = f >> 4;                  // 16 bf16x8 per row
    int kc = (f & 15) << 3;
    *(bf16x8*)&Bs[r * ROWE + kc] = *(const bf16x8*)&Wt[(size_t)r * K + kc];
  }

  // gather full g1 rows: 4 threads/row, 32 cols each
  {
    const int srow = tid >> 2;
    const int sl = tid & 3;
    const int gr = row0 + srow;
    const int cb = sl * 32;
    float a[32];
#pragma unroll
    for (int q = 0; q < 32; ++q) a[q] = 0.f;
    if (gr < M) {
      int es = offs[gr];
      int ee = offs[gr + 1];
      float dvv = dinv[gr];
      const short* rs = &Hs[(size_t)gr * HID + cb];
#pragma unroll
      for (int h = 0; h < 4; ++h) {
        bf16x8 sv = *(const bf16x8*)(rs + h * 8);
#pragma unroll
        for (int q = 0; q < 8; ++q) a[h * 8 + q] = bf2f(sv[q]);
      }
      int p = es;
      for (; p + 4 <= ee; p += 4) {
        int u0 = __builtin_nontemporal_load(&csr[p + 0]);
        int u1 = __builtin_nontemporal_load(&csr[p + 1]);
        int u2 = __builtin_nontemporal_load(&csr[p + 2]);
        int u3 = __builtin_nontemporal_load(&csr[p + 3]);
        const short* r0 = &Hs[(size_t)u0 * HID + cb];
        const short* r1 = &Hs[(size_t)u1 * HID + cb];
        const short* r2 = &Hs[(size_t)u2 * HID + cb];
        const short* r3 = &Hs[(size_t)u3 * HID + cb];
#pragma unroll
        for (int h = 0; h < 4; ++h) {
          bf16x8 x0 = *(const bf16x8*)(r0 + h * 8);
          bf16x8 x1 = *(const bf16x8*)(r1 + h * 8);
          bf16x8 x2 = *(const bf16x8*)(r2 + h * 8);
          bf16x8 x3 = *(const bf16x8*)(r3 + h * 8);
#pragma unroll
          for (int q = 0; q < 8; ++q)
            a[h * 8 + q] += (bf2f(x0[q]) + bf2f(x1[q])) +
                            (bf2f(x2[q]) + bf2f(x3[q]));
        }
      }
      for (; p < ee; ++p) {
        int u = __builtin_nontemporal_load(&csr[p]);
        const short* r0 = &Hs[(size_t)u * HID + cb];
#pragma unroll
        for (int h = 0; h < 4; ++h) {
          bf16x8 x = *(const bf16x8*)(r0 + h * 8);
#pragma unroll
          for (int q = 0; q < 8; ++q) a[h * 8 + q] += bf2f(x[q]);
        }
      }
#pragma unroll
      for (int h = 0; h < 8; ++h) {
        float4 bb = *(const float4*)&b1[cb + h * 4];
        a[h * 4 + 0] = fmaxf(fmaf(a[h * 4 + 0], dvv, bb.x), 0.f);
        a[h * 4 + 1] = fmaxf(fmaf(a[h * 4 + 1], dvv, bb.y), 0.f);
        a[h * 4 + 2] = fmaxf(fmaf(a[h * 4 + 2], dvv, bb.z), 0.f);
        a[h * 4 + 3] = fmaxf(fmaf(a[h * 4 + 3], dvv, bb.w), 0.f);
      }
    }
#pragma unroll
    for (int h = 0; h < 4; ++h) {
      bf16x8 o;
#pragma unroll
      for (int q = 0; q < 8; ++q) o[q] = f2bf(a[h * 8 + q]);
      *(bf16x8*)&As[srow * ROWE + cb + h * 8] = o;
    }
  }
  __syncthreads();  // single barrier: everything staged

  f32x4 acc[2][4] = {};
#pragma unroll
  for (int ks = 0; ks < 4; ++ks) {
    bf16x8 af[2], bfr[4];
#pragma unroll
    for (int mf = 0; mf < 2; ++mf)
      af[mf] = *(const bf16x8*)&As[(mh + mf * 16 + l15) * ROWE + ks * 32 + lk * 8];
#pragma unroll
    for (int nf = 0; nf < 4; ++nf)
      bfr[nf] = *(const bf16x8*)&Bs[(nh + nf * 16 + l15) * ROWE + ks * 32 + lk * 8];
#pragma unroll
    for (int mf = 0; mf < 2; ++mf)
#pragma unroll
      for (int nf = 0; nf < 4; ++nf)
        acc[mf][nf] = __builtin_amdgcn_mfma_f32_16x16x32_bf16(
            af[mf], bfr[nf], acc[mf][nf], 0, 0, 0);
  }
#pragma unroll
  for (int mf = 0; mf < 2; ++mf) {
#pragma unroll
    for (int r = 0; r < 4; ++r) {
      int lr = mh + mf * 16 + lk * 4 + r;
      int g2 = row0 + lr;
      if (g2 >= M) continue;
      float s = dln[lr];
#pragma unroll
      for (int nf = 0; nf < 4; ++nf)
        C[(size_t)g2 * HID + nh + nf * 16 + l15] = f2bf(acc[mf][nf][r] * s);
    }
  }
}

// --- AGG2 + mean-pool stage 1 (fused; no Hs2 writeback):
//   g2[v] = relu(dinv[v]*(Hs2[v] + sum_in Hs2[u]) + b2); sums[batch[v]] += g2[v]
// 512 threads: 64 nodes/block, 8 lanes/node x 16 cols, unroll x8/x4/x1.
__global__ __launch_bounds__(512) void agg2_pool_k(const short* __restrict__ Hs,
                                                   const int* __restrict__ offs,
                                                   const int* __restrict__ csr,
                                                   const float* __restrict__ dinv,
                                                   const float* __restrict__ b2,
                                                   const int* __restrict__ batch,
                                                   float* __restrict__ sums,
                                                   int N) {
  const int nid = threadIdx.x >> 3;   // 0..63
  const int l8 = threadIdx.x & 7;     // owns 16 cols
  const int v = blockIdx.x * 64 + nid;
  const int cb = l8 * 16;
  float a[16];
#pragma unroll
  for (int q = 0; q < 16; ++q) a[q] = 0.f;
  const bool valid = v < N;
  if (valid) {
    int es = offs[v];
    int ee = offs[v + 1];
    const short* rs = &Hs[(size_t)v * HID + cb];
    bf16x8 s0 = *(const bf16x8*)rs;
    bf16x8 s1 = *(const bf16x8*)(rs + 8);
#pragma unroll
    for (int q = 0; q < 8; ++q) { a[q] = bf2f(s0[q]); a[8 + q] = bf2f(s1[q]); }
    int p = es;
    for (; p + 8 <= ee; p += 8) {
      int u[8];
#pragma unroll
      for (int q = 0; q < 8; ++q) u[q] = __builtin_nontemporal_load(&csr[p + q]);
      bf16x8 xa[8], xb[8];
#pragma unroll
      for (int q = 0; q < 8; ++q) {
        const short* r0 = &Hs[(size_t)u[q] * HID + cb];
        xa[q] = *(const bf16x8*)r0;
        xb[q] = *(const bf16x8*)(r0 + 8);
      }
#pragma unroll
      for (int q = 0; q < 8; ++q)
#pragma unroll
        for (int r = 0; r < 8; ++r) {
          a[r] += bf2f(xa[q][r]);
          a[8 + r] += bf2f(xb[q][r]);
        }
    }
    for (; p + 4 <= ee; p += 4) {
      int u0 = __builtin_nontemporal_load(&csr[p + 0]);
      int u1 = __builtin_nontemporal_load(&csr[p + 1]);
      int u2 = __builtin_nontemporal_load(&csr[p + 2]);
      int u3 = __builtin_nontemporal_load(&csr[p + 3]);
      const short* r0 = &Hs[(size_t)u0 * HID + cb];
      const short* r1 = &Hs[(size_t)u1 * HID + cb];
      const short* r2 = &Hs[(size_t)u2 * HID + cb];
      const short* r3 = &Hs[(size_t)u3 * HID + cb];
      bf16x8 x0a = *(const bf16x8*)r0, x0b = *(const bf16x8*)(r0 + 8);
      bf16x8 x1a = *(const bf16x8*)r1, x1b = *(const bf16x8*)(r1 + 8);
      bf16x8 x2a = *(const bf16x8*)r2, x2b = *(const bf16x8*)(r2 + 8);
      bf16x8 x3a = *(const bf16x8*)r3, x3b = *(const bf16x8*)(r3 + 8);
#pragma unroll
      for (int q = 0; q < 8; ++q) {
        a[q]     += (bf2f(x0a[q]) + bf2f(x1a[q])) + (bf2f(x2a[q]) + bf2f(x3a[q]));
        a[8 + q] += (bf2f(x0b[q]) + bf2f(x1b[q])) + (bf2f(x2b[q]) + bf2f(x3b[q]));
      }
    }
    for (; p < ee; ++p) {
      int u = __builtin_nontemporal_load(&csr[p]);
      const short* r0 = &Hs[(size_t)u * HID + cb];
      bf16x8 xa = *(const bf16x8*)r0, xb = *(const bf16x8*)(r0 + 8);
#pragma unroll
      for (int q = 0; q < 8; ++q) { a[q] += bf2f(xa[q]); a[8 + q] += bf2f(xb[q]); }
    }
    float dv = dinv[v];
    float4 bb0 = *(const float4*)&b2[cb];
    float4 bb1 = *(const float4*)&b2[cb + 4];
    float4 bb2v = *(const float4*)&b2[cb + 8];
    float4 bb3 = *(const float4*)&b2[cb + 12];
    float bbv[16] = {bb0.x, bb0.y, bb0.z, bb0.w, bb1.x, bb1.y, bb1.z, bb1.w,
                     bb2v.x, bb2v.y, bb2v.z, bb2v.w, bb3.x, bb3.y, bb3.z, bb3.w};
#pragma unroll
    for (int q = 0; q < 16; ++q)
      a[q] = fmaxf(fmaf(a[q], dv, bbv[q]), 0.f);
  }
  // pool: segmented LDS reduce over sorted batch -> atomicAdd into sums
  __shared__ float ot[64 * 133];  // stride 133 floats to spread banks
  __shared__ int bsm[64];
#pragma unroll
  for (int q = 0; q < 16; ++q) ot[nid * 133 + cb + q] = a[q];
  if (threadIdx.x < 64) {
    int vv = blockIdx.x * 64 + threadIdx.x;
    bsm[threadIdx.x] = batch[vv < N ? vv : N - 1];  // invalid rows carry a=0
  }
  __syncthreads();
  int j = threadIdx.x & 127;  // column
  int h = threadIdx.x >> 7;   // 4 groups of 16 rows
  int r0 = h * 16;
  int g_cur = bsm[r0];
  float acc = 0.f;
#pragma unroll
  for (int rr = r0; rr < r0 + 16; ++rr) {
    int g = bsm[rr];
    if (g != g_cur) {
      atomicAdd(&sums[(size_t)g_cur * HID + j], acc);
      acc = 0.f;
      g_cur = g;
    }
    acc += ot[rr * 133 + j];
  }
  atomicAdd(&sums[(size_t)g_cur * HID + j], acc);
}

// --- head: pooled = sums/cnt; fused = relu([seq|pooled] @ Wf + bf); outputs ---
__global__ __launch_bounds__(128) void head_k(const float* __restrict__ seq,
                                              const float* __restrict__ sums,
                                              const int* __restrict__ batch,
                                              const float* __restrict__ Wf,
                                              const float* __restrict__ bf,
                                              const float* __restrict__ Wtp,
                                              const float* __restrict__ btp,
                                              const float* __restrict__ Wp,
                                              const float* __restrict__ bp,
                                              float* __restrict__ outp,
                                              int B, int SEQ, int n) {
  int g = blockIdx.x;
  int t = threadIdx.x;
  __shared__ float xin[512];
  __shared__ float fs[128];
  int lo = 0, hi = n;
  while (lo < hi) { int mid = (lo + hi) >> 1; if (batch[mid] < g) lo = mid + 1; else hi = mid; }
  int start = lo;
  hi = n;
  while (lo < hi) { int mid = (lo + hi) >> 1; if (batch[mid] <= g) lo = mid + 1; else hi = mid; }
  float inv_cnt = 1.f / fmaxf((float)(lo - start), 1.f);
  for (int i = t; i < SEQ; i += 128) xin[i] = seq[(size_t)g * SEQ + i];
  xin[SEQ + t] = sums[g * HID + t] * inv_cnt;
  __syncthreads();
  float acc = bf[t];
#pragma unroll 8
  for (int k = 0; k < 512; ++k) acc = fmaf(xin[k], Wf[(size_t)k * HID + t], acc);
  fs[t] = fmaxf(acc, 0.f);
  __syncthreads();
  if (t == 0) {
    float a0 = btp[0], a1 = btp[1], a2 = bp[0];
    for (int k = 0; k < 128; ++k) {
      float f = fs[k];
      a0 = fmaf(f, Wtp[k * 2 + 0], a0);
      a1 = fmaf(f, Wtp[k * 2 + 1], a1);
      a2 = fmaf(f, Wp[k], a2);
    }
    outp[g * 2 + 0] = a0;
    outp[g * 2 + 1] = a1;
    outp[B * 2 + g] = a2;
  }
}

extern "C" void kernel_launch(void* const* d_in, const int* in_sizes, int n_in,
                              void* d_out, int out_size, void* d_ws, size_t ws_size,
                              hipStream_t stream) {
  const float* seq_emb = (const float*)d_in[0];
  const float* node_x  = (const float*)d_in[1];
  const int*   eidx    = (const int*)d_in[2];
  const int*   nbatch  = (const int*)d_in[3];
  const float* W1  = (const float*)d_in[4];
  const float* b1  = (const float*)d_in[5];
  const float* W2  = (const float*)d_in[6];
  const float* b2  = (const float*)d_in[7];
  const float* Wf  = (const float*)d_in[8];
  const float* bfb = (const float*)d_in[9];
  const float* Wtp = (const float*)d_in[10];
  const float* btp = (const float*)d_in[11];
  const float* Wp  = (const float*)d_in[12];
  const float* bp  = (const float*)d_in[13];

  const int N = in_sizes[3];           // 50000 nodes
  const int E = in_sizes[2] / 2;       // 600000 edges
  const int SEQ = 384;
  const int B = in_sizes[0] / SEQ;     // 64 graphs

  char* w = (char*)d_ws;
  auto alloc = [&](size_t bytes) -> void* {
    void* p = (void*)w;
    w += (bytes + 255) & ~(size_t)255;
    return p;
  };
  float* dinv   = (float*)alloc((size_t)N * 4);
  int*   deg    = (int*)alloc((size_t)N * 4);
  int*   cur    = (int*)alloc((size_t)N * 4);
  int*   offs   = (int*)alloc((size_t)(N + 1) * 4);
  int*   bsum   = (int*)alloc(1024);
  int*   csr    = (int*)alloc((size_t)E * 4);
  short* W1t    = (short*)alloc((size_t)SEQ * HID * 2);
  short* W2t    = (short*)alloc((size_t)HID * HID * 2);
  short* bufC   = (short*)alloc((size_t)N * HID * 2);   // Hs1 bf16
  short* bufD   = (short*)alloc((size_t)N * HID * 2);   // Hs2 bf16
  float* sums   = (float*)alloc((size_t)B * HID * 4);

  const int* srcp = eidx;
  const int* dstp = eidx + E;

  int gE = (E + 255) / 256;
  int gN = (N + 255) / 256;  // 196 <= 256 (required by inline bsum scan)
  int wElems = SEQ * HID + HID * HID;
  int gP = (max(wElems, N) + 255) / 256;

  prep_w_k<<<gP, 256, 0, stream>>>(W1, W1t, W2, W2t, deg, N);
  hist_k<<<gE, 256, 0, stream>>>(dstp, deg, E);
  scan_bsum<<<gN, 256, 0, stream>>>(deg, bsum, dinv, N);
  scan_offsets<<<gN, 256, 0, stream>>>(deg, bsum, offs, cur, sums, B * HID, N, gN);
  fill_k<<<gE, 256, 0, stream>>>(srcp, dstp, offs, cur, csr, E);

  int gG = (N + 63) / 64;
  mfma_gemm1_k<<<gG, 256, 0, stream>>>(node_x, W1t, dinv, bufC, N);
  gemm2_agg_k<<<gG, 256, 0, stream>>>(bufC, offs, csr, dinv, b1, W2t, bufD, N);
  agg2_pool_k<<<gG, 512, 0, stream>>>(bufD, offs, csr, dinv, b2, nbatch, sums, N);
  head_k<<<B, 128, 0, stream>>>(seq_emb, sums, nbatch, Wf, bfb, Wtp, btp, Wp, bp,
                                (float*)d_out, B, SEQ, N);
}

// Round 11
// 208.349 us; speedup vs baseline: 1.0083x; 1.0083x over previous
//
#include <hip/hip_runtime.h>

// ---------------------------------------------------------------------------
// 2-layer GCN + mean-pool + MLP head.
// R9: agg1 fused into gemm2 A-staging; pool fused into agg2 (194 us).
// R10 (REVERTED): 52KB-LDS single-pass halved occupancy (21.6%) on a
//   latency-bound gather; NT csr loads defeated L2 reuse. Both reverted.
// R11: hybrid gemm2_agg — single full-row gather pass (As[64][136], halves
//   edge-loop iters + csr reads) but Bs staged per 64-k-half (LDS ~36KB ->
//   4 blocks/CU). 3 barriers. agg2_pool back to R9 form.
// ---------------------------------------------------------------------------

#define HID 128

typedef __attribute__((ext_vector_type(8))) short bf16x8;
typedef __attribute__((ext_vector_type(4))) short bf16x4;
typedef __attribute__((ext_vector_type(4))) float f32x4;

static __device__ __forceinline__ short f2bf(float f) {
  union { float f; unsigned u; } v; v.f = f;
  unsigned r = v.u + 0x7fff + ((v.u >> 16) & 1);  // RNE
  return (short)(r >> 16);
}
static __device__ __forceinline__ float bf2f(short s) {
  union { unsigned u; float f; } v;
  v.u = ((unsigned)(unsigned short)s) << 16;
  return v.f;
}

// --- W1/W2 fp32 -> Wt bf16 (transpose + convert) + zero deg (fused) ---
__global__ __launch_bounds__(256) void prep_w_k(const float* __restrict__ W1,
                                                short* __restrict__ W1t,
                                                const float* __restrict__ W2,
                                                short* __restrict__ W2t,
                                                int* __restrict__ deg, int N) {
  int idx = blockIdx.x * 256 + threadIdx.x;
  if (idx < 384 * HID) {
    int k = idx >> 7;
    int c = idx & 127;
    W1t[(size_t)c * 384 + k] = f2bf(W1[idx]);
  } else if (idx < 384 * HID + HID * HID) {
    int j = idx - 384 * HID;
    int k = j >> 7;
    int c = j & 127;
    W2t[(size_t)c * HID + k] = f2bf(W2[j]);
  }
  if (idx < N) deg[idx] = 0;
}

__global__ __launch_bounds__(256) void hist_k(const int* __restrict__ dst,
                                              int* __restrict__ cnt, int E) {
  int i = blockIdx.x * 256 + threadIdx.x;
  if (i < E) atomicAdd(&cnt[dst[i]], 1);
}

// per-256-chunk sums of deg + dinv computation (fused)
__global__ __launch_bounds__(256) void scan_bsum(const int* __restrict__ cnt,
                                                 int* __restrict__ bsum,
                                                 float* __restrict__ dinv, int n) {
  __shared__ int sm[256];
  int i = blockIdx.x * 256 + threadIdx.x;
  int v = (i < n) ? cnt[i] : 0;
  if (i < n) dinv[i] = rsqrtf((float)(v + 1));  // +1 self-loop
  sm[threadIdx.x] = v;
  __syncthreads();
  for (int off = 128; off > 0; off >>= 1) {
    if (threadIdx.x < off) sm[threadIdx.x] += sm[threadIdx.x + off];
    __syncthreads();
  }
  if (threadIdx.x == 0) bsum[blockIdx.x] = sm[0];
}

// offsets: inline exclusive scan of bsum (nb<=256) + per-chunk scan
//          + cur=0 + sums=0 (fused zeroing)
__global__ __launch_bounds__(256) void scan_offsets(const int* __restrict__ cnt,
                                                    const int* __restrict__ bsum,
                                                    int* __restrict__ offs,
                                                    int* __restrict__ cur,
                                                    float* __restrict__ sums,
                                                    int nsum, int n, int nb) {
  __shared__ int sm[256];
  int t = threadIdx.x;
  int bid = blockIdx.x;
  int zi = bid * 256 + t;
  if (zi < nsum) sums[zi] = 0.f;
  // pass 1: inclusive scan of bsum in LDS
  int bv = (t < nb) ? bsum[t] : 0;
  sm[t] = bv;
  __syncthreads();
  for (int off = 1; off < 256; off <<= 1) {
    int add = (t >= off) ? sm[t - off] : 0;
    __syncthreads();
    sm[t] += add;
    __syncthreads();
  }
  int base = (bid > 0) ? sm[bid - 1] : 0;  // exclusive prefix for this block
  __syncthreads();
  // pass 2: scan this block's 256-deg chunk
  int i = bid * 256 + t;
  int v = (i < n) ? cnt[i] : 0;
  sm[t] = v;
  __syncthreads();
  for (int off = 1; off < 256; off <<= 1) {
    int add = (t >= off) ? sm[t - off] : 0;
    __syncthreads();
    sm[t] += add;
    __syncthreads();
  }
  if (i < n) {
    offs[i] = base + sm[t] - v;
    cur[i] = 0;
  }
  if (i == n - 1) offs[n] = base + sm[t];  // total
}

__global__ __launch_bounds__(256) void fill_k(const int* __restrict__ src,
                                              const int* __restrict__ dst,
                                              const int* __restrict__ offs,
                                              int* __restrict__ cur,
                                              int* __restrict__ csr, int E) {
  int i = blockIdx.x * 256 + threadIdx.x;
  if (i >= E) return;
  int d = dst[i];
  int p = offs[d] + atomicAdd(&cur[d], 1);
  csr[p] = src[i];
}

// --- GEMM1: Hs1[M][128] = bf16( (node_x[M][384] @ W1t^T) * dinv[row] ) ---
// 64x128 tile, 4 waves (2x2 of 32x64), BK=64, mfma_f32_16x16x32_bf16.
__global__ __launch_bounds__(256) void mfma_gemm1_k(const float* __restrict__ Af,
                                                    const short* __restrict__ Wt,
                                                    const float* __restrict__ scale,
                                                    short* __restrict__ C, int M) {
  constexpr int K = 384;
  constexpr int BK = 64;
  constexpr int ROWE = BK + 8;  // 72 shorts = 144B rows (16B aligned)
  __shared__ short As[64 * ROWE];
  __shared__ short Bs[128 * ROWE];
  __shared__ float dln[64];

  const int tid = threadIdx.x;
  const int wave = tid >> 6;
  const int lane = tid & 63;
  const int l15 = lane & 15;
  const int lk = lane >> 4;          // k-group 0..3
  const int mh = (wave >> 1) * 32;   // wave row offset in tile
  const int nh = (wave & 1) * 64;    // wave col offset
  const int row0 = blockIdx.x * 64;

  if (tid < 64) {
    int r = row0 + tid;
    dln[tid] = (r < M) ? scale[r] : 0.f;
  }

  f32x4 acc[2][4] = {};

  for (int k0 = 0; k0 < K; k0 += BK) {
    __syncthreads();  // previous iter's LDS reads done before overwrite
#pragma unroll
    for (int it = 0; it < 4; ++it) {
      int f = tid + it * 256;
      int r = f >> 4;
      int kc = (f & 15) << 2;
      int gr = row0 + r;
      float4 v = make_float4(0.f, 0.f, 0.f, 0.f);
      if (gr < M) v = *(const float4*)&Af[(size_t)gr * K + k0 + kc];
      bf16x4 s;
      s[0] = f2bf(v.x); s[1] = f2bf(v.y); s[2] = f2bf(v.z); s[3] = f2bf(v.w);
      *(bf16x4*)&As[r * ROWE + kc] = s;
    }
#pragma unroll
    for (int it = 0; it < 4; ++it) {
      int f = tid + it * 256;
      int r = f >> 3;
      int kc = (f & 7) << 3;
      *(bf16x8*)&Bs[r * ROWE + kc] =
          *(const bf16x8*)&Wt[(size_t)r * K + k0 + kc];
    }
    __syncthreads();
#pragma unroll
    for (int ks = 0; ks < 2; ++ks) {
      bf16x8 af[2], bfr[4];
#pragma unroll
      for (int mf = 0; mf < 2; ++mf)
        af[mf] = *(const bf16x8*)&As[(mh + mf * 16 + l15) * ROWE + ks * 32 + lk * 8];
#pragma unroll
      for (int nf = 0; nf < 4; ++nf)
        bfr[nf] = *(const bf16x8*)&Bs[(nh + nf * 16 + l15) * ROWE + ks * 32 + lk * 8];
#pragma unroll
      for (int mf = 0; mf < 2; ++mf)
#pragma unroll
        for (int nf = 0; nf < 4; ++nf)
          acc[mf][nf] = __builtin_amdgcn_mfma_f32_16x16x32_bf16(
              af[mf], bfr[nf], acc[mf][nf], 0, 0, 0);
    }
  }
  // epilogue: C/D layout col=lane&15, row=(lane>>4)*4+reg
#pragma unroll
  for (int mf = 0; mf < 2; ++mf) {
#pragma unroll
    for (int r = 0; r < 4; ++r) {
      int lr = mh + mf * 16 + lk * 4 + r;
      int gr = row0 + lr;
      if (gr >= M) continue;
      float s = dln[lr];
#pragma unroll
      for (int nf = 0; nf < 4; ++nf)
        C[(size_t)gr * HID + nh + nf * 16 + l15] = f2bf(acc[mf][nf][r] * s);
    }
  }
}

// --- GEMM2 with fused AGG1, hybrid single-gather:
//   As[64][136] holds full g1 rows (gathered ONCE: 4 thr/row x 32 cols,
//   unroll x4 -> 16x16B in flight); Bs[128][72] holds one 64-wide k-half,
//   staged twice. LDS ~36KB -> 4 blocks/CU (occupancy preserved).
__global__ __launch_bounds__(256) void gemm2_agg_k(const short* __restrict__ Hs,
                                                   const int* __restrict__ offs,
                                                   const int* __restrict__ csr,
                                                   const float* __restrict__ dinv,
                                                   const float* __restrict__ b1,
                                                   const short* __restrict__ Wt,
                                                   short* __restrict__ C, int M) {
  constexpr int K = 128;
  constexpr int AROWE = K + 8;    // 136 shorts (full row)
  constexpr int BROWE = 64 + 8;   // 72 shorts (one k-half)
  __shared__ short As[64 * AROWE];
  __shared__ short Bs[128 * BROWE];
  __shared__ float dln[64];

  const int tid = threadIdx.x;
  const int wave = tid >> 6;
  const int lane = tid & 63;
  const int l15 = lane & 15;
  const int lk = lane >> 4;
  const int mh = (wave >> 1) * 32;
  const int nh = (wave & 1) * 64;
  const int row0 = blockIdx.x * 64;

  if (tid < 64) {
    int r = row0 + tid;
    dln[tid] = (r < M) ? dinv[r] : 0.f;
  }

  // stage Bs for k-half 0 (issue before the gather so it overlaps)
#pragma unroll
  for (int it = 0; it < 4; ++it) {
    int f = tid + it * 256;
    int r = f >> 3;
    int kc = (f & 7) << 3;
    *(bf16x8*)&Bs[r * BROWE + kc] = *(const bf16x8*)&Wt[(size_t)r * K + kc];
  }

  // gather full g1 rows ONCE: 4 threads/row, 32 cols each
  {
    const int srow = tid >> 2;
    const int sl = tid & 3;
    const int gr = row0 + srow;
    const int cb = sl * 32;
    float a[32];
#pragma unroll
    for (int q = 0; q < 32; ++q) a[q] = 0.f;
    if (gr < M) {
      int es = offs[gr];
      int ee = offs[gr + 1];
      float dvv = dinv[gr];
      const short* rs = &Hs[(size_t)gr * HID + cb];
#pragma unroll
      for (int h = 0; h < 4; ++h) {
        bf16x8 sv = *(const bf16x8*)(rs + h * 8);
#pragma unroll
        for (int q = 0; q < 8; ++q) a[h * 8 + q] = bf2f(sv[q]);
      }
      int p = es;
      for (; p + 4 <= ee; p += 4) {
        int u0 = csr[p + 0];
        int u1 = csr[p + 1];
        int u2 = csr[p + 2];
        int u3 = csr[p + 3];
        const short* r0 = &Hs[(size_t)u0 * HID + cb];
        const short* r1 = &Hs[(size_t)u1 * HID + cb];
        const short* r2 = &Hs[(size_t)u2 * HID + cb];
        const short* r3 = &Hs[(size_t)u3 * HID + cb];
#pragma unroll
        for (int h = 0; h < 4; ++h) {
          bf16x8 x0 = *(const bf16x8*)(r0 + h * 8);
          bf16x8 x1 = *(const bf16x8*)(r1 + h * 8);
          bf16x8 x2 = *(const bf16x8*)(r2 + h * 8);
          bf16x8 x3 = *(const bf16x8*)(r3 + h * 8);
#pragma unroll
          for (int q = 0; q < 8; ++q)
            a[h * 8 + q] += (bf2f(x0[q]) + bf2f(x1[q])) +
                            (bf2f(x2[q]) + bf2f(x3[q]));
        }
      }
      for (; p < ee; ++p) {
        int u = csr[p];
        const short* r0 = &Hs[(size_t)u * HID + cb];
#pragma unroll
        for (int h = 0; h < 4; ++h) {
          bf16x8 x = *(const bf16x8*)(r0 + h * 8);
#pragma unroll
          for (int q = 0; q < 8; ++q) a[h * 8 + q] += bf2f(x[q]);
        }
      }
#pragma unroll
      for (int h = 0; h < 8; ++h) {
        float4 bb = *(const float4*)&b1[cb + h * 4];
        a[h * 4 + 0] = fmaxf(fmaf(a[h * 4 + 0], dvv, bb.x), 0.f);
        a[h * 4 + 1] = fmaxf(fmaf(a[h * 4 + 1], dvv, bb.y), 0.f);
        a[h * 4 + 2] = fmaxf(fmaf(a[h * 4 + 2], dvv, bb.z), 0.f);
        a[h * 4 + 3] = fmaxf(fmaf(a[h * 4 + 3], dvv, bb.w), 0.f);
      }
    }
#pragma unroll
    for (int h = 0; h < 4; ++h) {
      bf16x8 o;
#pragma unroll
      for (int q = 0; q < 8; ++q) o[q] = f2bf(a[h * 8 + q]);
      *(bf16x8*)&As[srow * AROWE + cb + h * 8] = o;
    }
  }
  __syncthreads();  // As complete + Bs half 0 complete

  f32x4 acc[2][4] = {};
#pragma unroll
  for (int half = 0; half < 2; ++half) {
    if (half == 1) {
      __syncthreads();  // half-0 MFMA reads of Bs done
#pragma unroll
      for (int it = 0; it < 4; ++it) {
        int f = tid + it * 256;
        int r = f >> 3;
        int kc = (f & 7) << 3;
        *(bf16x8*)&Bs[r * BROWE + kc] =
            *(const bf16x8*)&Wt[(size_t)r * K + 64 + kc];
      }
      __syncthreads();
    }
#pragma unroll
    for (int ks = 0; ks < 2; ++ks) {
      bf16x8 af[2], bfr[4];
#pragma unroll
      for (int mf = 0; mf < 2; ++mf)
        af[mf] = *(const bf16x8*)
            &As[(mh + mf * 16 + l15) * AROWE + half * 64 + ks * 32 + lk * 8];
#pragma unroll
      for (int nf = 0; nf < 4; ++nf)
        bfr[nf] = *(const bf16x8*)
            &Bs[(nh + nf * 16 + l15) * BROWE + ks * 32 + lk * 8];
#pragma unroll
      for (int mf = 0; mf < 2; ++mf)
#pragma unroll
        for (int nf = 0; nf < 4; ++nf)
          acc[mf][nf] = __builtin_amdgcn_mfma_f32_16x16x32_bf16(
              af[mf], bfr[nf], acc[mf][nf], 0, 0, 0);
    }
  }
#pragma unroll
  for (int mf = 0; mf < 2; ++mf) {
#pragma unroll
    for (int r = 0; r < 4; ++r) {
      int lr = mh + mf * 16 + lk * 4 + r;
      int g2 = row0 + lr;
      if (g2 >= M) continue;
      float s = dln[lr];
#pragma unroll
      for (int nf = 0; nf < 4; ++nf)
        C[(size_t)g2 * HID + nh + nf * 16 + l15] = f2bf(acc[mf][nf][r] * s);
    }
  }
}

// --- AGG2 + mean-pool stage 1 (fused; no Hs2 writeback):
//   g2[v] = relu(dinv[v]*(Hs2[v] + sum_in Hs2[u]) + b2); sums[batch[v]] += g2[v]
// 512 threads: 64 nodes/block, 8 lanes/node x 16 cols (2x bf16x8 per edge).
__global__ __launch_bounds__(512) void agg2_pool_k(const short* __restrict__ Hs,
                                                   const int* __restrict__ offs,
                                                   const int* __restrict__ csr,
                                                   const float* __restrict__ dinv,
                                                   const float* __restrict__ b2,
                                                   const int* __restrict__ batch,
                                                   float* __restrict__ sums,
                                                   int N) {
  const int nid = threadIdx.x >> 3;   // 0..63
  const int l8 = threadIdx.x & 7;     // owns 16 cols
  const int v = blockIdx.x * 64 + nid;
  const int cb = l8 * 16;
  float a[16];
#pragma unroll
  for (int q = 0; q < 16; ++q) a[q] = 0.f;
  const bool valid = v < N;
  if (valid) {
    int es = offs[v];
    int ee = offs[v + 1];
    const short* rs = &Hs[(size_t)v * HID + cb];
    bf16x8 s0 = *(const bf16x8*)rs;
    bf16x8 s1 = *(const bf16x8*)(rs + 8);
#pragma unroll
    for (int q = 0; q < 8; ++q) { a[q] = bf2f(s0[q]); a[8 + q] = bf2f(s1[q]); }
    int p = es;
    for (; p + 4 <= ee; p += 4) {
      int u0 = csr[p + 0];
      int u1 = csr[p + 1];
      int u2 = csr[p + 2];
      int u3 = csr[p + 3];
      const short* r0 = &Hs[(size_t)u0 * HID + cb];
      const short* r1 = &Hs[(size_t)u1 * HID + cb];
      const short* r2 = &Hs[(size_t)u2 * HID + cb];
      const short* r3 = &Hs[(size_t)u3 * HID + cb];
      bf16x8 x0a = *(const bf16x8*)r0, x0b = *(const bf16x8*)(r0 + 8);
      bf16x8 x1a = *(const bf16x8*)r1, x1b = *(const bf16x8*)(r1 + 8);
      bf16x8 x2a = *(const bf16x8*)r2, x2b = *(const bf16x8*)(r2 + 8);
      bf16x8 x3a = *(const bf16x8*)r3, x3b = *(const bf16x8*)(r3 + 8);
#pragma unroll
      for (int q = 0; q < 8; ++q) {
        a[q]     += (bf2f(x0a[q]) + bf2f(x1a[q])) + (bf2f(x2a[q]) + bf2f(x3a[q]));
        a[8 + q] += (bf2f(x0b[q]) + bf2f(x1b[q])) + (bf2f(x2b[q]) + bf2f(x3b[q]));
      }
    }
    for (; p < ee; ++p) {
      int u = csr[p];
      const short* r0 = &Hs[(size_t)u * HID + cb];
      bf16x8 xa = *(const bf16x8*)r0, xb = *(const bf16x8*)(r0 + 8);
#pragma unroll
      for (int q = 0; q < 8; ++q) { a[q] += bf2f(xa[q]); a[8 + q] += bf2f(xb[q]); }
    }
    float dv = dinv[v];
    float4 bb0 = *(const float4*)&b2[cb];
    float4 bb1 = *(const float4*)&b2[cb + 4];
    float4 bb2v = *(const float4*)&b2[cb + 8];
    float4 bb3 = *(const float4*)&b2[cb + 12];
    float bbv[16] = {bb0.x, bb0.y, bb0.z, bb0.w, bb1.x, bb1.y, bb1.z, bb1.w,
                     bb2v.x, bb2v.y, bb2v.z, bb2v.w, bb3.x, bb3.y, bb3.z, bb3.w};
#pragma unroll
    for (int q = 0; q < 16; ++q)
      a[q] = fmaxf(fmaf(a[q], dv, bbv[q]), 0.f);
  }
  // pool: segmented LDS reduce over sorted batch -> atomicAdd into sums
  __shared__ float ot[64 * 133];  // stride 133 floats to spread banks
  __shared__ int bsm[64];
#pragma unroll
  for (int q = 0; q < 16; ++q) ot[nid * 133 + cb + q] = a[q];
  if (threadIdx.x < 64) {
    int vv = blockIdx.x * 64 + threadIdx.x;
    bsm[threadIdx.x] = batch[vv < N ? vv : N - 1];  // invalid rows carry a=0
  }
  __syncthreads();
  int j = threadIdx.x & 127;  // column
  int h = threadIdx.x >> 7;   // 4 groups of 16 rows
  int r0 = h * 16;
  int g_cur = bsm[r0];
  float acc = 0.f;
#pragma unroll
  for (int rr = r0; rr < r0 + 16; ++rr) {
    int g = bsm[rr];
    if (g != g_cur) {
      atomicAdd(&sums[(size_t)g_cur * HID + j], acc);
      acc = 0.f;
      g_cur = g;
    }
    acc += ot[rr * 133 + j];
  }
  atomicAdd(&sums[(size_t)g_cur * HID + j], acc);
}

// --- head: pooled = sums/cnt; fused = relu([seq|pooled] @ Wf + bf); outputs ---
__global__ __launch_bounds__(128) void head_k(const float* __restrict__ seq,
                                              const float* __restrict__ sums,
                                              const int* __restrict__ batch,
                                              const float* __restrict__ Wf,
                                              const float* __restrict__ bf,
                                              const float* __restrict__ Wtp,
                                              const float* __restrict__ btp,
                                              const float* __restrict__ Wp,
                                              const float* __restrict__ bp,
                                              float* __restrict__ outp,
                                              int B, int SEQ, int n) {
  int g = blockIdx.x;
  int t = threadIdx.x;
  __shared__ float xin[512];
  __shared__ float fs[128];
  int lo = 0, hi = n;
  while (lo < hi) { int mid = (lo + hi) >> 1; if (batch[mid] < g) lo = mid + 1; else hi = mid; }
  int start = lo;
  hi = n;
  while (lo < hi) { int mid = (lo + hi) >> 1; if (batch[mid] <= g) lo = mid + 1; else hi = mid; }
  float inv_cnt = 1.f / fmaxf((float)(lo - start), 1.f);
  for (int i = t; i < SEQ; i += 128) xin[i] = seq[(size_t)g * SEQ + i];
  xin[SEQ + t] = sums[g * HID + t] * inv_cnt;
  __syncthreads();
  float acc = bf[t];
#pragma unroll 8
  for (int k = 0; k < 512; ++k) acc = fmaf(xin[k], Wf[(size_t)k * HID + t], acc);
  fs[t] = fmaxf(acc, 0.f);
  __syncthreads();
  if (t == 0) {
    float a0 = btp[0], a1 = btp[1], a2 = bp[0];
    for (int k = 0; k < 128; ++k) {
      float f = fs[k];
      a0 = fmaf(f, Wtp[k * 2 + 0], a0);
      a1 = fmaf(f, Wtp[k * 2 + 1], a1);
      a2 = fmaf(f, Wp[k], a2);
    }
    outp[g * 2 + 0] = a0;
    outp[g * 2 + 1] = a1;
    outp[B * 2 + g] = a2;
  }
}

extern "C" void kernel_launch(void* const* d_in, const int* in_sizes, int n_in,
                              void* d_out, int out_size, void* d_ws, size_t ws_size,
                              hipStream_t stream) {
  const float* seq_emb = (const float*)d_in[0];
  const float* node_x  = (const float*)d_in[1];
  const int*   eidx    = (const int*)d_in[2];
  const int*   nbatch  = (const int*)d_in[3];
  const float* W1  = (const float*)d_in[4];
  const float* b1  = (const float*)d_in[5];
  const float* W2  = (const float*)d_in[6];
  const float* b2  = (const float*)d_in[7];
  const float* Wf  = (const float*)d_in[8];
  const float* bfb = (const float*)d_in[9];
  const float* Wtp = (const float*)d_in[10];
  const float* btp = (const float*)d_in[11];
  const float* Wp  = (const float*)d_in[12];
  const float* bp  = (const float*)d_in[13];

  const int N = in_sizes[3];           // 50000 nodes
  const int E = in_sizes[2] / 2;       // 600000 edges
  const int SEQ = 384;
  const int B = in_sizes[0] / SEQ;     // 64 graphs

  char* w = (char*)d_ws;
  auto alloc = [&](size_t bytes) -> void* {
    void* p = (void*)w;
    w += (bytes + 255) & ~(size_t)255;
    return p;
  };
  float* dinv   = (float*)alloc((size_t)N * 4);
  int*   deg    = (int*)alloc((size_t)N * 4);
  int*   cur    = (int*)alloc((size_t)N * 4);
  int*   offs   = (int*)alloc((size_t)(N + 1) * 4);
  int*   bsum   = (int*)alloc(1024);
  int*   csr    = (int*)alloc((size_t)E * 4);
  short* W1t    = (short*)alloc((size_t)SEQ * HID * 2);
  short* W2t    = (short*)alloc((size_t)HID * HID * 2);
  short* bufC   = (short*)alloc((size_t)N * HID * 2);   // Hs1 bf16
  short* bufD   = (short*)alloc((size_t)N * HID * 2);   // Hs2 bf16
  float* sums   = (float*)alloc((size_t)B * HID * 4);

  const int* srcp = eidx;
  const int* dstp = eidx + E;

  int gE = (E + 255) / 256;
  int gN = (N + 255) / 256;  // 196 <= 256 (required by inline bsum scan)
  int wElems = SEQ * HID + HID * HID;
  int gP = (max(wElems, N) + 255) / 256;

  prep_w_k<<<gP, 256, 0, stream>>>(W1, W1t, W2, W2t, deg, N);
  hist_k<<<gE, 256, 0, stream>>>(dstp, deg, E);
  scan_bsum<<<gN, 256, 0, stream>>>(deg, bsum, dinv, N);
  scan_offsets<<<gN, 256, 0, stream>>>(deg, bsum, offs, cur, sums, B * HID, N, gN);
  fill_k<<<gE, 256, 0, stream>>>(srcp, dstp, offs, cur, csr, E);

  int gG = (N + 63) / 64;
  mfma_gemm1_k<<<gG, 256, 0, stream>>>(node_x, W1t, dinv, bufC, N);
  gemm2_agg_k<<<gG, 256, 0, stream>>>(bufC, offs, csr, dinv, b1, W2t, bufD, N);
  agg2_pool_k<<<gG, 512, 0, stream>>>(bufD, offs, csr, dinv, b2, nbatch, sums, N);
  head_k<<<B, 128, 0, stream>>>(seq_emb, sums, nbatch, Wf, bfb, Wtp, btp, Wp, bp,
                                (float*)d_out, B, SEQ, N);
}

// Round 12
// 192.185 us; speedup vs baseline: 1.0931x; 1.0841x over previous
//
#include <hip/hip_runtime.h>

// ---------------------------------------------------------------------------
// 2-layer GCN + mean-pool + MLP head.
// R9: agg1 fused into gemm2 A-staging (two-pass 128B slices); pool fused into
//     agg2. 194 us. R10/R11 (REVERTED): single-pass 256B-row gather is +14us
//     regardless of LDS size — narrower slices/pass gather faster.
// R12: exact R9 structure; single variable: edge-unroll x8 in gemm2_agg's
//     gather passes (16x16B in flight per thread).
// ---------------------------------------------------------------------------

#define HID 128

typedef __attribute__((ext_vector_type(8))) short bf16x8;
typedef __attribute__((ext_vector_type(4))) short bf16x4;
typedef __attribute__((ext_vector_type(4))) float f32x4;

static __device__ __forceinline__ short f2bf(float f) {
  union { float f; unsigned u; } v; v.f = f;
  unsigned r = v.u + 0x7fff + ((v.u >> 16) & 1);  // RNE
  return (short)(r >> 16);
}
static __device__ __forceinline__ float bf2f(short s) {
  union { unsigned u; float f; } v;
  v.u = ((unsigned)(unsigned short)s) << 16;
  return v.f;
}

// --- W1/W2 fp32 -> Wt bf16 (transpose + convert) + zero deg (fused) ---
__global__ __launch_bounds__(256) void prep_w_k(const float* __restrict__ W1,
                                                short* __restrict__ W1t,
                                                const float* __restrict__ W2,
                                                short* __restrict__ W2t,
                                                int* __restrict__ deg, int N) {
  int idx = blockIdx.x * 256 + threadIdx.x;
  if (idx < 384 * HID) {
    int k = idx >> 7;
    int c = idx & 127;
    W1t[(size_t)c * 384 + k] = f2bf(W1[idx]);
  } else if (idx < 384 * HID + HID * HID) {
    int j = idx - 384 * HID;
    int k = j >> 7;
    int c = j & 127;
    W2t[(size_t)c * HID + k] = f2bf(W2[j]);
  }
  if (idx < N) deg[idx] = 0;
}

__global__ __launch_bounds__(256) void hist_k(const int* __restrict__ dst,
                                              int* __restrict__ cnt, int E) {
  int i = blockIdx.x * 256 + threadIdx.x;
  if (i < E) atomicAdd(&cnt[dst[i]], 1);
}

// per-256-chunk sums of deg + dinv computation (fused)
__global__ __launch_bounds__(256) void scan_bsum(const int* __restrict__ cnt,
                                                 int* __restrict__ bsum,
                                                 float* __restrict__ dinv, int n) {
  __shared__ int sm[256];
  int i = blockIdx.x * 256 + threadIdx.x;
  int v = (i < n) ? cnt[i] : 0;
  if (i < n) dinv[i] = rsqrtf((float)(v + 1));  // +1 self-loop
  sm[threadIdx.x] = v;
  __syncthreads();
  for (int off = 128; off > 0; off >>= 1) {
    if (threadIdx.x < off) sm[threadIdx.x] += sm[threadIdx.x + off];
    __syncthreads();
  }
  if (threadIdx.x == 0) bsum[blockIdx.x] = sm[0];
}

// offsets: inline exclusive scan of bsum (nb<=256) + per-chunk scan
//          + cur=0 + sums=0 (fused zeroing)
__global__ __launch_bounds__(256) void scan_offsets(const int* __restrict__ cnt,
                                                    const int* __restrict__ bsum,
                                                    int* __restrict__ offs,
                                                    int* __restrict__ cur,
                                                    float* __restrict__ sums,
                                                    int nsum, int n, int nb) {
  __shared__ int sm[256];
  int t = threadIdx.x;
  int bid = blockIdx.x;
  int zi = bid * 256 + t;
  if (zi < nsum) sums[zi] = 0.f;
  // pass 1: inclusive scan of bsum in LDS
  int bv = (t < nb) ? bsum[t] : 0;
  sm[t] = bv;
  __syncthreads();
  for (int off = 1; off < 256; off <<= 1) {
    int add = (t >= off) ? sm[t - off] : 0;
    __syncthreads();
    sm[t] += add;
    __syncthreads();
  }
  int base = (bid > 0) ? sm[bid - 1] : 0;  // exclusive prefix for this block
  __syncthreads();
  // pass 2: scan this block's 256-deg chunk
  int i = bid * 256 + t;
  int v = (i < n) ? cnt[i] : 0;
  sm[t] = v;
  __syncthreads();
  for (int off = 1; off < 256; off <<= 1) {
    int add = (t >= off) ? sm[t - off] : 0;
    __syncthreads();
    sm[t] += add;
    __syncthreads();
  }
  if (i < n) {
    offs[i] = base + sm[t] - v;
    cur[i] = 0;
  }
  if (i == n - 1) offs[n] = base + sm[t];  // total
}

__global__ __launch_bounds__(256) void fill_k(const int* __restrict__ src,
                                              const int* __restrict__ dst,
                                              const int* __restrict__ offs,
                                              int* __restrict__ cur,
                                              int* __restrict__ csr, int E) {
  int i = blockIdx.x * 256 + threadIdx.x;
  if (i >= E) return;
  int d = dst[i];
  int p = offs[d] + atomicAdd(&cur[d], 1);
  csr[p] = src[i];
}

// --- GEMM1: Hs1[M][128] = bf16( (node_x[M][384] @ W1t^T) * dinv[row] ) ---
// 64x128 tile, 4 waves (2x2 of 32x64), BK=64, mfma_f32_16x16x32_bf16.
__global__ __launch_bounds__(256) void mfma_gemm1_k(const float* __restrict__ Af,
                                                    const short* __restrict__ Wt,
                                                    const float* __restrict__ scale,
                                                    short* __restrict__ C, int M) {
  constexpr int K = 384;
  constexpr int BK = 64;
  constexpr int ROWE = BK + 8;  // 72 shorts = 144B rows (16B aligned)
  __shared__ short As[64 * ROWE];
  __shared__ short Bs[128 * ROWE];
  __shared__ float dln[64];

  const int tid = threadIdx.x;
  const int wave = tid >> 6;
  const int lane = tid & 63;
  const int l15 = lane & 15;
  const int lk = lane >> 4;          // k-group 0..3
  const int mh = (wave >> 1) * 32;   // wave row offset in tile
  const int nh = (wave & 1) * 64;    // wave col offset
  const int row0 = blockIdx.x * 64;

  if (tid < 64) {
    int r = row0 + tid;
    dln[tid] = (r < M) ? scale[r] : 0.f;
  }

  f32x4 acc[2][4] = {};

  for (int k0 = 0; k0 < K; k0 += BK) {
    __syncthreads();  // previous iter's LDS reads done before overwrite
#pragma unroll
    for (int it = 0; it < 4; ++it) {
      int f = tid + it * 256;
      int r = f >> 4;
      int kc = (f & 15) << 2;
      int gr = row0 + r;
      float4 v = make_float4(0.f, 0.f, 0.f, 0.f);
      if (gr < M) v = *(const float4*)&Af[(size_t)gr * K + k0 + kc];
      bf16x4 s;
      s[0] = f2bf(v.x); s[1] = f2bf(v.y); s[2] = f2bf(v.z); s[3] = f2bf(v.w);
      *(bf16x4*)&As[r * ROWE + kc] = s;
    }
#pragma unroll
    for (int it = 0; it < 4; ++it) {
      int f = tid + it * 256;
      int r = f >> 3;
      int kc = (f & 7) << 3;
      *(bf16x8*)&Bs[r * ROWE + kc] =
          *(const bf16x8*)&Wt[(size_t)r * K + k0 + kc];
    }
    __syncthreads();
#pragma unroll
    for (int ks = 0; ks < 2; ++ks) {
      bf16x8 af[2], bfr[4];
#pragma unroll
      for (int mf = 0; mf < 2; ++mf)
        af[mf] = *(const bf16x8*)&As[(mh + mf * 16 + l15) * ROWE + ks * 32 + lk * 8];
#pragma unroll
      for (int nf = 0; nf < 4; ++nf)
        bfr[nf] = *(const bf16x8*)&Bs[(nh + nf * 16 + l15) * ROWE + ks * 32 + lk * 8];
#pragma unroll
      for (int mf = 0; mf < 2; ++mf)
#pragma unroll
        for (int nf = 0; nf < 4; ++nf)
          acc[mf][nf] = __builtin_amdgcn_mfma_f32_16x16x32_bf16(
              af[mf], bfr[nf], acc[mf][nf], 0, 0, 0);
    }
  }
  // epilogue: C/D layout col=lane&15, row=(lane>>4)*4+reg
#pragma unroll
  for (int mf = 0; mf < 2; ++mf) {
#pragma unroll
    for (int r = 0; r < 4; ++r) {
      int lr = mh + mf * 16 + lk * 4 + r;
      int gr = row0 + lr;
      if (gr >= M) continue;
      float s = dln[lr];
#pragma unroll
      for (int nf = 0; nf < 4; ++nf)
        C[(size_t)gr * HID + nh + nf * 16 + l15] = f2bf(acc[mf][nf][r] * s);
    }
  }
}

// --- GEMM2 with fused AGG1 A-staging (R9 two-pass form, edge unroll x8):
//   per k-step, each row's 64-col slice of g1 is aggregated on the fly:
//   g1[v][c] = relu(dinv[v]*(Hs1[v][c] + sum_in Hs1[u][c]) + b1[c]).
//   4 threads/row x 16 cols (2x bf16x8 per edge); two passes (k0=0,64).
__global__ __launch_bounds__(256) void gemm2_agg_k(const short* __restrict__ Hs,
                                                   const int* __restrict__ offs,
                                                   const int* __restrict__ csr,
                                                   const float* __restrict__ dinv,
                                                   const float* __restrict__ b1,
                                                   const short* __restrict__ Wt,
                                                   short* __restrict__ C, int M) {
  constexpr int K = 128;
  constexpr int BK = 64;
  constexpr int ROWE = BK + 8;
  __shared__ short As[64 * ROWE];
  __shared__ short Bs[128 * ROWE];
  __shared__ float dln[64];

  const int tid = threadIdx.x;
  const int wave = tid >> 6;
  const int lane = tid & 63;
  const int l15 = lane & 15;
  const int lk = lane >> 4;
  const int mh = (wave >> 1) * 32;
  const int nh = (wave & 1) * 64;
  const int row0 = blockIdx.x * 64;

  if (tid < 64) {
    int r = row0 + tid;
    dln[tid] = (r < M) ? dinv[r] : 0.f;
  }

  // staging thread mapping: 4 threads per row, 16 cols each
  const int srow = tid >> 2;
  const int sl = tid & 3;
  const int gr = row0 + srow;
  const bool valid = gr < M;
  int es = 0, ee = 0;
  float dvv = 0.f;
  if (valid) {
    es = offs[gr];
    ee = offs[gr + 1];
    dvv = dinv[gr];
  }

  f32x4 acc[2][4] = {};

  for (int k0 = 0; k0 < K; k0 += BK) {
    __syncthreads();
    // stage Wt [128][64]
#pragma unroll
    for (int it = 0; it < 4; ++it) {
      int f = tid + it * 256;
      int r = f >> 3;
      int kc = (f & 7) << 3;
      *(bf16x8*)&Bs[r * ROWE + kc] =
          *(const bf16x8*)&Wt[(size_t)r * K + k0 + kc];
    }
    // stage A via on-the-fly aggregation of cols [k0+sl*16, +16)
    {
      const int cb = k0 + sl * 16;
      float a[16];
#pragma unroll
      for (int q = 0; q < 16; ++q) a[q] = 0.f;
      if (valid) {
        const short* rs = &Hs[(size_t)gr * HID + cb];
        bf16x8 s0 = *(const bf16x8*)rs;
        bf16x8 s1 = *(const bf16x8*)(rs + 8);
#pragma unroll
        for (int q = 0; q < 8; ++q) { a[q] = bf2f(s0[q]); a[8 + q] = bf2f(s1[q]); }
        int p = es;
        for (; p + 8 <= ee; p += 8) {
          int u[8];
#pragma unroll
          for (int q = 0; q < 8; ++q) u[q] = csr[p + q];
          bf16x8 xa[8], xb[8];
#pragma unroll
          for (int q = 0; q < 8; ++q) {
            const short* r0 = &Hs[(size_t)u[q] * HID + cb];
            xa[q] = *(const bf16x8*)r0;
            xb[q] = *(const bf16x8*)(r0 + 8);
          }
#pragma unroll
          for (int q = 0; q < 8; ++q)
#pragma unroll
            for (int r = 0; r < 8; ++r) {
              a[r] += bf2f(xa[q][r]);
              a[8 + r] += bf2f(xb[q][r]);
            }
        }
        for (; p + 4 <= ee; p += 4) {
          int u0 = csr[p + 0];
          int u1 = csr[p + 1];
          int u2 = csr[p + 2];
          int u3 = csr[p + 3];
          const short* r0 = &Hs[(size_t)u0 * HID + cb];
          const short* r1 = &Hs[(size_t)u1 * HID + cb];
          const short* r2 = &Hs[(size_t)u2 * HID + cb];
          const short* r3 = &Hs[(size_t)u3 * HID + cb];
          bf16x8 x0a = *(const bf16x8*)r0, x0b = *(const bf16x8*)(r0 + 8);
          bf16x8 x1a = *(const bf16x8*)r1, x1b = *(const bf16x8*)(r1 + 8);
          bf16x8 x2a = *(const bf16x8*)r2, x2b = *(const bf16x8*)(r2 + 8);
          bf16x8 x3a = *(const bf16x8*)r3, x3b = *(const bf16x8*)(r3 + 8);
#pragma unroll
          for (int q = 0; q < 8; ++q) {
            a[q]     += (bf2f(x0a[q]) + bf2f(x1a[q])) + (bf2f(x2a[q]) + bf2f(x3a[q]));
            a[8 + q] += (bf2f(x0b[q]) + bf2f(x1b[q])) + (bf2f(x2b[q]) + bf2f(x3b[q]));
          }
        }
        for (; p < ee; ++p) {
          int u = csr[p];
          const short* r0 = &Hs[(size_t)u * HID + cb];
          bf16x8 xa = *(const bf16x8*)r0, xb = *(const bf16x8*)(r0 + 8);
#pragma unroll
          for (int q = 0; q < 8; ++q) { a[q] += bf2f(xa[q]); a[8 + q] += bf2f(xb[q]); }
        }
        float4 bb0 = *(const float4*)&b1[cb];
        float4 bb1 = *(const float4*)&b1[cb + 4];
        float4 bb2 = *(const float4*)&b1[cb + 8];
        float4 bb3 = *(const float4*)&b1[cb + 12];
        float bbv[16] = {bb0.x, bb0.y, bb0.z, bb0.w, bb1.x, bb1.y, bb1.z, bb1.w,
                         bb2.x, bb2.y, bb2.z, bb2.w, bb3.x, bb3.y, bb3.z, bb3.w};
#pragma unroll
        for (int q = 0; q < 16; ++q)
          a[q] = fmaxf(fmaf(a[q], dvv, bbv[q]), 0.f);
      }
      bf16x8 o0, o1;
#pragma unroll
      for (int q = 0; q < 8; ++q) { o0[q] = f2bf(a[q]); o1[q] = f2bf(a[8 + q]); }
      *(bf16x8*)&As[srow * ROWE + sl * 16] = o0;
      *(bf16x8*)&As[srow * ROWE + sl * 16 + 8] = o1;
    }
    __syncthreads();
#pragma unroll
    for (int ks = 0; ks < 2; ++ks) {
      bf16x8 af[2], bfr[4];
#pragma unroll
      for (int mf = 0; mf < 2; ++mf)
        af[mf] = *(const bf16x8*)&As[(mh + mf * 16 + l15) * ROWE + ks * 32 + lk * 8];
#pragma unroll
      for (int nf = 0; nf < 4; ++nf)
        bfr[nf] = *(const bf16x8*)&Bs[(nh + nf * 16 + l15) * ROWE + ks * 32 + lk * 8];
#pragma unroll
      for (int mf = 0; mf < 2; ++mf)
#pragma unroll
        for (int nf = 0; nf < 4; ++nf)
          acc[mf][nf] = __builtin_amdgcn_mfma_f32_16x16x32_bf16(
              af[mf], bfr[nf], acc[mf][nf], 0, 0, 0);
    }
  }
#pragma unroll
  for (int mf = 0; mf < 2; ++mf) {
#pragma unroll
    for (int r = 0; r < 4; ++r) {
      int lr = mh + mf * 16 + lk * 4 + r;
      int g2 = row0 + lr;
      if (g2 >= M) continue;
      float s = dln[lr];
#pragma unroll
      for (int nf = 0; nf < 4; ++nf)
        C[(size_t)g2 * HID + nh + nf * 16 + l15] = f2bf(acc[mf][nf][r] * s);
    }
  }
}

// --- AGG2 + mean-pool stage 1 (fused; no Hs2 writeback):
//   g2[v] = relu(dinv[v]*(Hs2[v] + sum_in Hs2[u]) + b2); sums[batch[v]] += g2[v]
// 512 threads: 64 nodes/block, 8 lanes/node x 16 cols (2x bf16x8 per edge).
__global__ __launch_bounds__(512) void agg2_pool_k(const short* __restrict__ Hs,
                                                   const int* __restrict__ offs,
                                                   const int* __restrict__ csr,
                                                   const float* __restrict__ dinv,
                                                   const float* __restrict__ b2,
                                                   const int* __restrict__ batch,
                                                   float* __restrict__ sums,
                                                   int N) {
  const int nid = threadIdx.x >> 3;   // 0..63
  const int l8 = threadIdx.x & 7;     // owns 16 cols
  const int v = blockIdx.x * 64 + nid;
  const int cb = l8 * 16;
  float a[16];
#pragma unroll
  for (int q = 0; q < 16; ++q) a[q] = 0.f;
  const bool valid = v < N;
  if (valid) {
    int es = offs[v];
    int ee = offs[v + 1];
    const short* rs = &Hs[(size_t)v * HID + cb];
    bf16x8 s0 = *(const bf16x8*)rs;
    bf16x8 s1 = *(const bf16x8*)(rs + 8);
#pragma unroll
    for (int q = 0; q < 8; ++q) { a[q] = bf2f(s0[q]); a[8 + q] = bf2f(s1[q]); }
    int p = es;
    for (; p + 4 <= ee; p += 4) {
      int u0 = csr[p + 0];
      int u1 = csr[p + 1];
      int u2 = csr[p + 2];
      int u3 = csr[p + 3];
      const short* r0 = &Hs[(size_t)u0 * HID + cb];
      const short* r1 = &Hs[(size_t)u1 * HID + cb];
      const short* r2 = &Hs[(size_t)u2 * HID + cb];
      const short* r3 = &Hs[(size_t)u3 * HID + cb];
      bf16x8 x0a = *(const bf16x8*)r0, x0b = *(const bf16x8*)(r0 + 8);
      bf16x8 x1a = *(const bf16x8*)r1, x1b = *(const bf16x8*)(r1 + 8);
      bf16x8 x2a = *(const bf16x8*)r2, x2b = *(const bf16x8*)(r2 + 8);
      bf16x8 x3a = *(const bf16x8*)r3, x3b = *(const bf16x8*)(r3 + 8);
#pragma unroll
      for (int q = 0; q < 8; ++q) {
        a[q]     += (bf2f(x0a[q]) + bf2f(x1a[q])) + (bf2f(x2a[q]) + bf2f(x3a[q]));
        a[8 + q] += (bf2f(x0b[q]) + bf2f(x1b[q])) + (bf2f(x2b[q]) + bf2f(x3b[q]));
      }
    }
    for (; p < ee; ++p) {
      int u = csr[p];
      const short* r0 = &Hs[(size_t)u * HID + cb];
      bf16x8 xa = *(const bf16x8*)r0, xb = *(const bf16x8*)(r0 + 8);
#pragma unroll
      for (int q = 0; q < 8; ++q) { a[q] += bf2f(xa[q]); a[8 + q] += bf2f(xb[q]); }
    }
    float dv = dinv[v];
    float4 bb0 = *(const float4*)&b2[cb];
    float4 bb1 = *(const float4*)&b2[cb + 4];
    float4 bb2v = *(const float4*)&b2[cb + 8];
    float4 bb3 = *(const float4*)&b2[cb + 12];
    float bbv[16] = {bb0.x, bb0.y, bb0.z, bb0.w, bb1.x, bb1.y, bb1.z, bb1.w,
                     bb2v.x, bb2v.y, bb2v.z, bb2v.w, bb3.x, bb3.y, bb3.z, bb3.w};
#pragma unroll
    for (int q = 0; q < 16; ++q)
      a[q] = fmaxf(fmaf(a[q], dv, bbv[q]), 0.f);
  }
  // pool: segmented LDS reduce over sorted batch -> atomicAdd into sums
  __shared__ float ot[64 * 133];  // stride 133 floats to spread banks
  __shared__ int bsm[64];
#pragma unroll
  for (int q = 0; q < 16; ++q) ot[nid * 133 + cb + q] = a[q];
  if (threadIdx.x < 64) {
    int vv = blockIdx.x * 64 + threadIdx.x;
    bsm[threadIdx.x] = batch[vv < N ? vv : N - 1];  // invalid rows carry a=0
  }
  __syncthreads();
  int j = threadIdx.x & 127;  // column
  int h = threadIdx.x >> 7;   // 4 groups of 16 rows
  int r0 = h * 16;
  int g_cur = bsm[r0];
  float acc = 0.f;
#pragma unroll
  for (int rr = r0; rr < r0 + 16; ++rr) {
    int g = bsm[rr];
    if (g != g_cur) {
      atomicAdd(&sums[(size_t)g_cur * HID + j], acc);
      acc = 0.f;
      g_cur = g;
    }
    acc += ot[rr * 133 + j];
  }
  atomicAdd(&sums[(size_t)g_cur * HID + j], acc);
}

// --- head: pooled = sums/cnt; fused = relu([seq|pooled] @ Wf + bf); outputs ---
__global__ __launch_bounds__(128) void head_k(const float* __restrict__ seq,
                                              const float* __restrict__ sums,
                                              const int* __restrict__ batch,
                                              const float* __restrict__ Wf,
                                              const float* __restrict__ bf,
                                              const float* __restrict__ Wtp,
                                              const float* __restrict__ btp,
                                              const float* __restrict__ Wp,
                                              const float* __restrict__ bp,
                                              float* __restrict__ outp,
                                              int B, int SEQ, int n) {
  int g = blockIdx.x;
  int t = threadIdx.x;
  __shared__ float xin[512];
  __shared__ float fs[128];
  int lo = 0, hi = n;
  while (lo < hi) { int mid = (lo + hi) >> 1; if (batch[mid] < g) lo = mid + 1; else hi = mid; }
  int start = lo;
  hi = n;
  while (lo < hi) { int mid = (lo + hi) >> 1; if (batch[mid] <= g) lo = mid + 1; else hi = mid; }
  float inv_cnt = 1.f / fmaxf((float)(lo - start), 1.f);
  for (int i = t; i < SEQ; i += 128) xin[i] = seq[(size_t)g * SEQ + i];
  xin[SEQ + t] = sums[g * HID + t] * inv_cnt;
  __syncthreads();
  float acc = bf[t];
#pragma unroll 8
  for (int k = 0; k < 512; ++k) acc = fmaf(xin[k], Wf[(size_t)k * HID + t], acc);
  fs[t] = fmaxf(acc, 0.f);
  __syncthreads();
  if (t == 0) {
    float a0 = btp[0], a1 = btp[1], a2 = bp[0];
    for (int k = 0; k < 128; ++k) {
      float f = fs[k];
      a0 = fmaf(f, Wtp[k * 2 + 0], a0);
      a1 = fmaf(f, Wtp[k * 2 + 1], a1);
      a2 = fmaf(f, Wp[k], a2);
    }
    outp[g * 2 + 0] = a0;
    outp[g * 2 + 1] = a1;
    outp[B * 2 + g] = a2;
  }
}

extern "C" void kernel_launch(void* const* d_in, const int* in_sizes, int n_in,
                              void* d_out, int out_size, void* d_ws, size_t ws_size,
                              hipStream_t stream) {
  const float* seq_emb = (const float*)d_in[0];
  const float* node_x  = (const float*)d_in[1];
  const int*   eidx    = (const int*)d_in[2];
  const int*   nbatch  = (const int*)d_in[3];
  const float* W1  = (const float*)d_in[4];
  const float* b1  = (const float*)d_in[5];
  const float* W2  = (const float*)d_in[6];
  const float* b2  = (const float*)d_in[7];
  const float* Wf  = (const float*)d_in[8];
  const float* bfb = (const float*)d_in[9];
  const float* Wtp = (const float*)d_in[10];
  const float* btp = (const float*)d_in[11];
  const float* Wp  = (const float*)d_in[12];
  const float* bp  = (const float*)d_in[13];

  const int N = in_sizes[3];           // 50000 nodes
  const int E = in_sizes[2] / 2;       // 600000 edges
  const int SEQ = 384;
  const int B = in_sizes[0] / SEQ;     // 64 graphs

  char* w = (char*)d_ws;
  auto alloc = [&](size_t bytes) -> void* {
    void* p = (void*)w;
    w += (bytes + 255) & ~(size_t)255;
    return p;
  };
  float* dinv   = (float*)alloc((size_t)N * 4);
  int*   deg    = (int*)alloc((size_t)N * 4);
  int*   cur    = (int*)alloc((size_t)N * 4);
  int*   offs   = (int*)alloc((size_t)(N + 1) * 4);
  int*   bsum   = (int*)alloc(1024);
  int*   csr    = (int*)alloc((size_t)E * 4);
  short* W1t    = (short*)alloc((size_t)SEQ * HID * 2);
  short* W2t    = (short*)alloc((size_t)HID * HID * 2);
  short* bufC   = (short*)alloc((size_t)N * HID * 2);   // Hs1 bf16
  short* bufD   = (short*)alloc((size_t)N * HID * 2);   // Hs2 bf16
  float* sums   = (float*)alloc((size_t)B * HID * 4);

  const int* srcp = eidx;
  const int* dstp = eidx + E;

  int gE = (E + 255) / 256;
  int gN = (N + 255) / 256;  // 196 <= 256 (required by inline bsum scan)
  int wElems = SEQ * HID + HID * HID;
  int gP = (max(wElems, N) + 255) / 256;

  prep_w_k<<<gP, 256, 0, stream>>>(W1, W1t, W2, W2t, deg, N);
  hist_k<<<gE, 256, 0, stream>>>(dstp, deg, E);
  scan_bsum<<<gN, 256, 0, stream>>>(deg, bsum, dinv, N);
  scan_offsets<<<gN, 256, 0, stream>>>(deg, bsum, offs, cur, sums, B * HID, N, gN);
  fill_k<<<gE, 256, 0, stream>>>(srcp, dstp, offs, cur, csr, E);

  int gG = (N + 63) / 64;
  mfma_gemm1_k<<<gG, 256, 0, stream>>>(node_x, W1t, dinv, bufC, N);
  gemm2_agg_k<<<gG, 256, 0, stream>>>(bufC, offs, csr, dinv, b1, W2t, bufD, N);
  agg2_pool_k<<<gG, 512, 0, stream>>>(bufD, offs, csr, dinv, b2, nbatch, sums, N);
  head_k<<<B, 128, 0, stream>>>(seq_emb, sums, nbatch, Wf, bfb, Wtp, btp, Wp, bp,
                                (float*)d_out, B, SEQ, N);
}

// Round 13
// 174.742 us; speedup vs baseline: 1.2022x; 1.0998x over previous
//
#include <hip/hip_runtime.h>

// ---------------------------------------------------------------------------
// 2-layer GCN + mean-pool + MLP head.
// R9/R12: agg1 fused into gemm2 A-staging (two-pass 128B slices, unroll x8);
//         pool fused into agg2. 192 us.
// R13: head_k was a hidden 44us latency bomb (64 blks x 128 thr, 512-long
//      dependent chain, serial tail). Now 512 thr: 4-way k-split + LDS
//      reduce + wave-0 shuffle-butterfly tail.
// ---------------------------------------------------------------------------

#define HID 128

typedef __attribute__((ext_vector_type(8))) short bf16x8;
typedef __attribute__((ext_vector_type(4))) short bf16x4;
typedef __attribute__((ext_vector_type(4))) float f32x4;

static __device__ __forceinline__ short f2bf(float f) {
  union { float f; unsigned u; } v; v.f = f;
  unsigned r = v.u + 0x7fff + ((v.u >> 16) & 1);  // RNE
  return (short)(r >> 16);
}
static __device__ __forceinline__ float bf2f(short s) {
  union { unsigned u; float f; } v;
  v.u = ((unsigned)(unsigned short)s) << 16;
  return v.f;
}

// --- W1/W2 fp32 -> Wt bf16 (transpose + convert) + zero deg (fused) ---
__global__ __launch_bounds__(256) void prep_w_k(const float* __restrict__ W1,
                                                short* __restrict__ W1t,
                                                const float* __restrict__ W2,
                                                short* __restrict__ W2t,
                                                int* __restrict__ deg, int N) {
  int idx = blockIdx.x * 256 + threadIdx.x;
  if (idx < 384 * HID) {
    int k = idx >> 7;
    int c = idx & 127;
    W1t[(size_t)c * 384 + k] = f2bf(W1[idx]);
  } else if (idx < 384 * HID + HID * HID) {
    int j = idx - 384 * HID;
    int k = j >> 7;
    int c = j & 127;
    W2t[(size_t)c * HID + k] = f2bf(W2[j]);
  }
  if (idx < N) deg[idx] = 0;
}

__global__ __launch_bounds__(256) void hist_k(const int* __restrict__ dst,
                                              int* __restrict__ cnt, int E) {
  int i = blockIdx.x * 256 + threadIdx.x;
  if (i < E) atomicAdd(&cnt[dst[i]], 1);
}

// per-256-chunk sums of deg + dinv computation (fused)
__global__ __launch_bounds__(256) void scan_bsum(const int* __restrict__ cnt,
                                                 int* __restrict__ bsum,
                                                 float* __restrict__ dinv, int n) {
  __shared__ int sm[256];
  int i = blockIdx.x * 256 + threadIdx.x;
  int v = (i < n) ? cnt[i] : 0;
  if (i < n) dinv[i] = rsqrtf((float)(v + 1));  // +1 self-loop
  sm[threadIdx.x] = v;
  __syncthreads();
  for (int off = 128; off > 0; off >>= 1) {
    if (threadIdx.x < off) sm[threadIdx.x] += sm[threadIdx.x + off];
    __syncthreads();
  }
  if (threadIdx.x == 0) bsum[blockIdx.x] = sm[0];
}

// offsets: inline exclusive scan of bsum (nb<=256) + per-chunk scan
//          + cur=0 + sums=0 (fused zeroing)
__global__ __launch_bounds__(256) void scan_offsets(const int* __restrict__ cnt,
                                                    const int* __restrict__ bsum,
                                                    int* __restrict__ offs,
                                                    int* __restrict__ cur,
                                                    float* __restrict__ sums,
                                                    int nsum, int n, int nb) {
  __shared__ int sm[256];
  int t = threadIdx.x;
  int bid = blockIdx.x;
  int zi = bid * 256 + t;
  if (zi < nsum) sums[zi] = 0.f;
  // pass 1: inclusive scan of bsum in LDS
  int bv = (t < nb) ? bsum[t] : 0;
  sm[t] = bv;
  __syncthreads();
  for (int off = 1; off < 256; off <<= 1) {
    int add = (t >= off) ? sm[t - off] : 0;
    __syncthreads();
    sm[t] += add;
    __syncthreads();
  }
  int base = (bid > 0) ? sm[bid - 1] : 0;  // exclusive prefix for this block
  __syncthreads();
  // pass 2: scan this block's 256-deg chunk
  int i = bid * 256 + t;
  int v = (i < n) ? cnt[i] : 0;
  sm[t] = v;
  __syncthreads();
  for (int off = 1; off < 256; off <<= 1) {
    int add = (t >= off) ? sm[t - off] : 0;
    __syncthreads();
    sm[t] += add;
    __syncthreads();
  }
  if (i < n) {
    offs[i] = base + sm[t] - v;
    cur[i] = 0;
  }
  if (i == n - 1) offs[n] = base + sm[t];  // total
}

__global__ __launch_bounds__(256) void fill_k(const int* __restrict__ src,
                                              const int* __restrict__ dst,
                                              const int* __restrict__ offs,
                                              int* __restrict__ cur,
                                              int* __restrict__ csr, int E) {
  int i = blockIdx.x * 256 + threadIdx.x;
  if (i >= E) return;
  int d = dst[i];
  int p = offs[d] + atomicAdd(&cur[d], 1);
  csr[p] = src[i];
}

// --- GEMM1: Hs1[M][128] = bf16( (node_x[M][384] @ W1t^T) * dinv[row] ) ---
// 64x128 tile, 4 waves (2x2 of 32x64), BK=64, mfma_f32_16x16x32_bf16.
__global__ __launch_bounds__(256) void mfma_gemm1_k(const float* __restrict__ Af,
                                                    const short* __restrict__ Wt,
                                                    const float* __restrict__ scale,
                                                    short* __restrict__ C, int M) {
  constexpr int K = 384;
  constexpr int BK = 64;
  constexpr int ROWE = BK + 8;  // 72 shorts = 144B rows (16B aligned)
  __shared__ short As[64 * ROWE];
  __shared__ short Bs[128 * ROWE];
  __shared__ float dln[64];

  const int tid = threadIdx.x;
  const int wave = tid >> 6;
  const int lane = tid & 63;
  const int l15 = lane & 15;
  const int lk = lane >> 4;          // k-group 0..3
  const int mh = (wave >> 1) * 32;   // wave row offset in tile
  const int nh = (wave & 1) * 64;    // wave col offset
  const int row0 = blockIdx.x * 64;

  if (tid < 64) {
    int r = row0 + tid;
    dln[tid] = (r < M) ? scale[r] : 0.f;
  }

  f32x4 acc[2][4] = {};

  for (int k0 = 0; k0 < K; k0 += BK) {
    __syncthreads();  // previous iter's LDS reads done before overwrite
#pragma unroll
    for (int it = 0; it < 4; ++it) {
      int f = tid + it * 256;
      int r = f >> 4;
      int kc = (f & 15) << 2;
      int gr = row0 + r;
      float4 v = make_float4(0.f, 0.f, 0.f, 0.f);
      if (gr < M) v = *(const float4*)&Af[(size_t)gr * K + k0 + kc];
      bf16x4 s;
      s[0] = f2bf(v.x); s[1] = f2bf(v.y); s[2] = f2bf(v.z); s[3] = f2bf(v.w);
      *(bf16x4*)&As[r * ROWE + kc] = s;
    }
#pragma unroll
    for (int it = 0; it < 4; ++it) {
      int f = tid + it * 256;
      int r = f >> 3;
      int kc = (f & 7) << 3;
      *(bf16x8*)&Bs[r * ROWE + kc] =
          *(const bf16x8*)&Wt[(size_t)r * K + k0 + kc];
    }
    __syncthreads();
#pragma unroll
    for (int ks = 0; ks < 2; ++ks) {
      bf16x8 af[2], bfr[4];
#pragma unroll
      for (int mf = 0; mf < 2; ++mf)
        af[mf] = *(const bf16x8*)&As[(mh + mf * 16 + l15) * ROWE + ks * 32 + lk * 8];
#pragma unroll
      for (int nf = 0; nf < 4; ++nf)
        bfr[nf] = *(const bf16x8*)&Bs[(nh + nf * 16 + l15) * ROWE + ks * 32 + lk * 8];
#pragma unroll
      for (int mf = 0; mf < 2; ++mf)
#pragma unroll
        for (int nf = 0; nf < 4; ++nf)
          acc[mf][nf] = __builtin_amdgcn_mfma_f32_16x16x32_bf16(
              af[mf], bfr[nf], acc[mf][nf], 0, 0, 0);
    }
  }
  // epilogue: C/D layout col=lane&15, row=(lane>>4)*4+reg
#pragma unroll
  for (int mf = 0; mf < 2; ++mf) {
#pragma unroll
    for (int r = 0; r < 4; ++r) {
      int lr = mh + mf * 16 + lk * 4 + r;
      int gr = row0 + lr;
      if (gr >= M) continue;
      float s = dln[lr];
#pragma unroll
      for (int nf = 0; nf < 4; ++nf)
        C[(size_t)gr * HID + nh + nf * 16 + l15] = f2bf(acc[mf][nf][r] * s);
    }
  }
}

// --- GEMM2 with fused AGG1 A-staging (two-pass, edge unroll x8) ---
__global__ __launch_bounds__(256) void gemm2_agg_k(const short* __restrict__ Hs,
                                                   const int* __restrict__ offs,
                                                   const int* __restrict__ csr,
                                                   const float* __restrict__ dinv,
                                                   const float* __restrict__ b1,
                                                   const short* __restrict__ Wt,
                                                   short* __restrict__ C, int M) {
  constexpr int K = 128;
  constexpr int BK = 64;
  constexpr int ROWE = BK + 8;
  __shared__ short As[64 * ROWE];
  __shared__ short Bs[128 * ROWE];
  __shared__ float dln[64];

  const int tid = threadIdx.x;
  const int wave = tid >> 6;
  const int lane = tid & 63;
  const int l15 = lane & 15;
  const int lk = lane >> 4;
  const int mh = (wave >> 1) * 32;
  const int nh = (wave & 1) * 64;
  const int row0 = blockIdx.x * 64;

  if (tid < 64) {
    int r = row0 + tid;
    dln[tid] = (r < M) ? dinv[r] : 0.f;
  }

  // staging thread mapping: 4 threads per row, 16 cols each
  const int srow = tid >> 2;
  const int sl = tid & 3;
  const int gr = row0 + srow;
  const bool valid = gr < M;
  int es = 0, ee = 0;
  float dvv = 0.f;
  if (valid) {
    es = offs[gr];
    ee = offs[gr + 1];
    dvv = dinv[gr];
  }

  f32x4 acc[2][4] = {};

  for (int k0 = 0; k0 < K; k0 += BK) {
    __syncthreads();
    // stage Wt [128][64]
#pragma unroll
    for (int it = 0; it < 4; ++it) {
      int f = tid + it * 256;
      int r = f >> 3;
      int kc = (f & 7) << 3;
      *(bf16x8*)&Bs[r * ROWE + kc] =
          *(const bf16x8*)&Wt[(size_t)r * K + k0 + kc];
    }
    // stage A via on-the-fly aggregation of cols [k0+sl*16, +16)
    {
      const int cb = k0 + sl * 16;
      float a[16];
#pragma unroll
      for (int q = 0; q < 16; ++q) a[q] = 0.f;
      if (valid) {
        const short* rs = &Hs[(size_t)gr * HID + cb];
        bf16x8 s0 = *(const bf16x8*)rs;
        bf16x8 s1 = *(const bf16x8*)(rs + 8);
#pragma unroll
        for (int q = 0; q < 8; ++q) { a[q] = bf2f(s0[q]); a[8 + q] = bf2f(s1[q]); }
        int p = es;
        for (; p + 8 <= ee; p += 8) {
          int u[8];
#pragma unroll
          for (int q = 0; q < 8; ++q) u[q] = csr[p + q];
          bf16x8 xa[8], xb[8];
#pragma unroll
          for (int q = 0; q < 8; ++q) {
            const short* r0 = &Hs[(size_t)u[q] * HID + cb];
            xa[q] = *(const bf16x8*)r0;
            xb[q] = *(const bf16x8*)(r0 + 8);
          }
#pragma unroll
          for (int q = 0; q < 8; ++q)
#pragma unroll
            for (int r = 0; r < 8; ++r) {
              a[r] += bf2f(xa[q][r]);
              a[8 + r] += bf2f(xb[q][r]);
            }
        }
        for (; p + 4 <= ee; p += 4) {
          int u0 = csr[p + 0];
          int u1 = csr[p + 1];
          int u2 = csr[p + 2];
          int u3 = csr[p + 3];
          const short* r0 = &Hs[(size_t)u0 * HID + cb];
          const short* r1 = &Hs[(size_t)u1 * HID + cb];
          const short* r2 = &Hs[(size_t)u2 * HID + cb];
          const short* r3 = &Hs[(size_t)u3 * HID + cb];
          bf16x8 x0a = *(const bf16x8*)r0, x0b = *(const bf16x8*)(r0 + 8);
          bf16x8 x1a = *(const bf16x8*)r1, x1b = *(const bf16x8*)(r1 + 8);
          bf16x8 x2a = *(const bf16x8*)r2, x2b = *(const bf16x8*)(r2 + 8);
          bf16x8 x3a = *(const bf16x8*)r3, x3b = *(const bf16x8*)(r3 + 8);
#pragma unroll
          for (int q = 0; q < 8; ++q) {
            a[q]     += (bf2f(x0a[q]) + bf2f(x1a[q])) + (bf2f(x2a[q]) + bf2f(x3a[q]));
            a[8 + q] += (bf2f(x0b[q]) + bf2f(x1b[q])) + (bf2f(x2b[q]) + bf2f(x3b[q]));
          }
        }
        for (; p < ee; ++p) {
          int u = csr[p];
          const short* r0 = &Hs[(size_t)u * HID + cb];
          bf16x8 xa = *(const bf16x8*)r0, xb = *(const bf16x8*)(r0 + 8);
#pragma unroll
          for (int q = 0; q < 8; ++q) { a[q] += bf2f(xa[q]); a[8 + q] += bf2f(xb[q]); }
        }
        float4 bb0 = *(const float4*)&b1[cb];
        float4 bb1 = *(const float4*)&b1[cb + 4];
        float4 bb2 = *(const float4*)&b1[cb + 8];
        float4 bb3 = *(const float4*)&b1[cb + 12];
        float bbv[16] = {bb0.x, bb0.y, bb0.z, bb0.w, bb1.x, bb1.y, bb1.z, bb1.w,
                         bb2.x, bb2.y, bb2.z, bb2.w, bb3.x, bb3.y, bb3.z, bb3.w};
#pragma unroll
        for (int q = 0; q < 16; ++q)
          a[q] = fmaxf(fmaf(a[q], dvv, bbv[q]), 0.f);
      }
      bf16x8 o0, o1;
#pragma unroll
      for (int q = 0; q < 8; ++q) { o0[q] = f2bf(a[q]); o1[q] = f2bf(a[8 + q]); }
      *(bf16x8*)&As[srow * ROWE + sl * 16] = o0;
      *(bf16x8*)&As[srow * ROWE + sl * 16 + 8] = o1;
    }
    __syncthreads();
#pragma unroll
    for (int ks = 0; ks < 2; ++ks) {
      bf16x8 af[2], bfr[4];
#pragma unroll
      for (int mf = 0; mf < 2; ++mf)
        af[mf] = *(const bf16x8*)&As[(mh + mf * 16 + l15) * ROWE + ks * 32 + lk * 8];
#pragma unroll
      for (int nf = 0; nf < 4; ++nf)
        bfr[nf] = *(const bf16x8*)&Bs[(nh + nf * 16 + l15) * ROWE + ks * 32 + lk * 8];
#pragma unroll
      for (int mf = 0; mf < 2; ++mf)
#pragma unroll
        for (int nf = 0; nf < 4; ++nf)
          acc[mf][nf] = __builtin_amdgcn_mfma_f32_16x16x32_bf16(
              af[mf], bfr[nf], acc[mf][nf], 0, 0, 0);
    }
  }
#pragma unroll
  for (int mf = 0; mf < 2; ++mf) {
#pragma unroll
    for (int r = 0; r < 4; ++r) {
      int lr = mh + mf * 16 + lk * 4 + r;
      int g2 = row0 + lr;
      if (g2 >= M) continue;
      float s = dln[lr];
#pragma unroll
      for (int nf = 0; nf < 4; ++nf)
        C[(size_t)g2 * HID + nh + nf * 16 + l15] = f2bf(acc[mf][nf][r] * s);
    }
  }
}

// --- AGG2 + mean-pool stage 1 (fused; no Hs2 writeback):
//   g2[v] = relu(dinv[v]*(Hs2[v] + sum_in Hs2[u]) + b2); sums[batch[v]] += g2[v]
// 512 threads: 64 nodes/block, 8 lanes/node x 16 cols (2x bf16x8 per edge).
__global__ __launch_bounds__(512) void agg2_pool_k(const short* __restrict__ Hs,
                                                   const int* __restrict__ offs,
                                                   const int* __restrict__ csr,
                                                   const float* __restrict__ dinv,
                                                   const float* __restrict__ b2,
                                                   const int* __restrict__ batch,
                                                   float* __restrict__ sums,
                                                   int N) {
  const int nid = threadIdx.x >> 3;   // 0..63
  const int l8 = threadIdx.x & 7;     // owns 16 cols
  const int v = blockIdx.x * 64 + nid;
  const int cb = l8 * 16;
  float a[16];
#pragma unroll
  for (int q = 0; q < 16; ++q) a[q] = 0.f;
  const bool valid = v < N;
  if (valid) {
    int es = offs[v];
    int ee = offs[v + 1];
    const short* rs = &Hs[(size_t)v * HID + cb];
    bf16x8 s0 = *(const bf16x8*)rs;
    bf16x8 s1 = *(const bf16x8*)(rs + 8);
#pragma unroll
    for (int q = 0; q < 8; ++q) { a[q] = bf2f(s0[q]); a[8 + q] = bf2f(s1[q]); }
    int p = es;
    for (; p + 4 <= ee; p += 4) {
      int u0 = csr[p + 0];
      int u1 = csr[p + 1];
      int u2 = csr[p + 2];
      int u3 = csr[p + 3];
      const short* r0 = &Hs[(size_t)u0 * HID + cb];
      const short* r1 = &Hs[(size_t)u1 * HID + cb];
      const short* r2 = &Hs[(size_t)u2 * HID + cb];
      const short* r3 = &Hs[(size_t)u3 * HID + cb];
      bf16x8 x0a = *(const bf16x8*)r0, x0b = *(const bf16x8*)(r0 + 8);
      bf16x8 x1a = *(const bf16x8*)r1, x1b = *(const bf16x8*)(r1 + 8);
      bf16x8 x2a = *(const bf16x8*)r2, x2b = *(const bf16x8*)(r2 + 8);
      bf16x8 x3a = *(const bf16x8*)r3, x3b = *(const bf16x8*)(r3 + 8);
#pragma unroll
      for (int q = 0; q < 8; ++q) {
        a[q]     += (bf2f(x0a[q]) + bf2f(x1a[q])) + (bf2f(x2a[q]) + bf2f(x3a[q]));
        a[8 + q] += (bf2f(x0b[q]) + bf2f(x1b[q])) + (bf2f(x2b[q]) + bf2f(x3b[q]));
      }
    }
    for (; p < ee; ++p) {
      int u = csr[p];
      const short* r0 = &Hs[(size_t)u * HID + cb];
      bf16x8 xa = *(const bf16x8*)r0, xb = *(const bf16x8*)(r0 + 8);
#pragma unroll
      for (int q = 0; q < 8; ++q) { a[q] += bf2f(xa[q]); a[8 + q] += bf2f(xb[q]); }
    }
    float dv = dinv[v];
    float4 bb0 = *(const float4*)&b2[cb];
    float4 bb1 = *(const float4*)&b2[cb + 4];
    float4 bb2v = *(const float4*)&b2[cb + 8];
    float4 bb3 = *(const float4*)&b2[cb + 12];
    float bbv[16] = {bb0.x, bb0.y, bb0.z, bb0.w, bb1.x, bb1.y, bb1.z, bb1.w,
                     bb2v.x, bb2v.y, bb2v.z, bb2v.w, bb3.x, bb3.y, bb3.z, bb3.w};
#pragma unroll
    for (int q = 0; q < 16; ++q)
      a[q] = fmaxf(fmaf(a[q], dv, bbv[q]), 0.f);
  }
  // pool: segmented LDS reduce over sorted batch -> atomicAdd into sums
  __shared__ float ot[64 * 133];  // stride 133 floats to spread banks
  __shared__ int bsm[64];
#pragma unroll
  for (int q = 0; q < 16; ++q) ot[nid * 133 + cb + q] = a[q];
  if (threadIdx.x < 64) {
    int vv = blockIdx.x * 64 + threadIdx.x;
    bsm[threadIdx.x] = batch[vv < N ? vv : N - 1];  // invalid rows carry a=0
  }
  __syncthreads();
  int j = threadIdx.x & 127;  // column
  int h = threadIdx.x >> 7;   // 4 groups of 16 rows
  int r0 = h * 16;
  int g_cur = bsm[r0];
  float acc = 0.f;
#pragma unroll
  for (int rr = r0; rr < r0 + 16; ++rr) {
    int g = bsm[rr];
    if (g != g_cur) {
      atomicAdd(&sums[(size_t)g_cur * HID + j], acc);
      acc = 0.f;
      g_cur = g;
    }
    acc += ot[rr * 133 + j];
  }
  atomicAdd(&sums[(size_t)g_cur * HID + j], acc);
}

// --- head (R13): 512 threads, 4-way k-split + LDS reduce + shuffle tail ---
__global__ __launch_bounds__(512) void head_k(const float* __restrict__ seq,
                                              const float* __restrict__ sums,
                                              const int* __restrict__ batch,
                                              const float* __restrict__ Wf,
                                              const float* __restrict__ bf,
                                              const float* __restrict__ Wtp,
                                              const float* __restrict__ btp,
                                              const float* __restrict__ Wp,
                                              const float* __restrict__ bp,
                                              float* __restrict__ outp,
                                              int B, int SEQ, int n) {
  int g = blockIdx.x;
  int t = threadIdx.x;
  __shared__ float xin[512];
  __shared__ float ps[4][128];
  __shared__ float fs[128];
  // per-graph node count via binary search over sorted batch (all threads)
  int lo = 0, hi = n;
  while (lo < hi) { int mid = (lo + hi) >> 1; if (batch[mid] < g) lo = mid + 1; else hi = mid; }
  int start = lo;
  hi = n;
  while (lo < hi) { int mid = (lo + hi) >> 1; if (batch[mid] <= g) lo = mid + 1; else hi = mid; }
  float inv_cnt = 1.f / fmaxf((float)(lo - start), 1.f);
  // stage xin: [seq(384) | pooled(128)]
  if (t < SEQ) xin[t] = seq[(size_t)g * SEQ + t];
  else xin[t] = sums[g * HID + (t - SEQ)] * inv_cnt;
  __syncthreads();
  // partial dot: thread (j = t&127, ks = t>>7) sums 128 k's
  int j = t & 127;
  int ks = t >> 7;
  int kb = ks * 128;
  float acc = 0.f;
#pragma unroll 8
  for (int k = 0; k < 128; ++k)
    acc = fmaf(xin[kb + k], Wf[(size_t)(kb + k) * HID + j], acc);
  ps[ks][j] = acc;
  __syncthreads();
  if (t < 128) {
    float s = ps[0][t] + ps[1][t] + ps[2][t] + ps[3][t] + bf[t];
    fs[t] = fmaxf(s, 0.f);
  }
  __syncthreads();
  // tail: wave 0 reduces the three tiny dots via shuffle butterfly
  if (t < 64) {
    float f0 = fs[t], f1 = fs[t + 64];
    float p0 = f0 * Wtp[t * 2]     + f1 * Wtp[(t + 64) * 2];
    float p1 = f0 * Wtp[t * 2 + 1] + f1 * Wtp[(t + 64) * 2 + 1];
    float p2 = f0 * Wp[t]          + f1 * Wp[t + 64];
#pragma unroll
    for (int off = 32; off > 0; off >>= 1) {
      p0 += __shfl_xor(p0, off);
      p1 += __shfl_xor(p1, off);
      p2 += __shfl_xor(p2, off);
    }
    if (t == 0) {
      outp[g * 2 + 0] = p0 + btp[0];
      outp[g * 2 + 1] = p1 + btp[1];
      outp[B * 2 + g] = p2 + bp[0];
    }
  }
}

extern "C" void kernel_launch(void* const* d_in, const int* in_sizes, int n_in,
                              void* d_out, int out_size, void* d_ws, size_t ws_size,
                              hipStream_t stream) {
  const float* seq_emb = (const float*)d_in[0];
  const float* node_x  = (const float*)d_in[1];
  const int*   eidx    = (const int*)d_in[2];
  const int*   nbatch  = (const int*)d_in[3];
  const float* W1  = (const float*)d_in[4];
  const float* b1  = (const float*)d_in[5];
  const float* W2  = (const float*)d_in[6];
  const float* b2  = (const float*)d_in[7];
  const float* Wf  = (const float*)d_in[8];
  const float* bfb = (const float*)d_in[9];
  const float* Wtp = (const float*)d_in[10];
  const float* btp = (const float*)d_in[11];
  const float* Wp  = (const float*)d_in[12];
  const float* bp  = (const float*)d_in[13];

  const int N = in_sizes[3];           // 50000 nodes
  const int E = in_sizes[2] / 2;       // 600000 edges
  const int SEQ = 384;
  const int B = in_sizes[0] / SEQ;     // 64 graphs

  char* w = (char*)d_ws;
  auto alloc = [&](size_t bytes) -> void* {
    void* p = (void*)w;
    w += (bytes + 255) & ~(size_t)255;
    return p;
  };
  float* dinv   = (float*)alloc((size_t)N * 4);
  int*   deg    = (int*)alloc((size_t)N * 4);
  int*   cur    = (int*)alloc((size_t)N * 4);
  int*   offs   = (int*)alloc((size_t)(N + 1) * 4);
  int*   bsum   = (int*)alloc(1024);
  int*   csr    = (int*)alloc((size_t)E * 4);
  short* W1t    = (short*)alloc((size_t)SEQ * HID * 2);
  short* W2t    = (short*)alloc((size_t)HID * HID * 2);
  short* bufC   = (short*)alloc((size_t)N * HID * 2);   // Hs1 bf16
  short* bufD   = (short*)alloc((size_t)N * HID * 2);   // Hs2 bf16
  float* sums   = (float*)alloc((size_t)B * HID * 4);

  const int* srcp = eidx;
  const int* dstp = eidx + E;

  int gE = (E + 255) / 256;
  int gN = (N + 255) / 256;  // 196 <= 256 (required by inline bsum scan)
  int wElems = SEQ * HID + HID * HID;
  int gP = (max(wElems, N) + 255) / 256;

  prep_w_k<<<gP, 256, 0, stream>>>(W1, W1t, W2, W2t, deg, N);
  hist_k<<<gE, 256, 0, stream>>>(dstp, deg, E);
  scan_bsum<<<gN, 256, 0, stream>>>(deg, bsum, dinv, N);
  scan_offsets<<<gN, 256, 0, stream>>>(deg, bsum, offs, cur, sums, B * HID, N, gN);
  fill_k<<<gE, 256, 0, stream>>>(srcp, dstp, offs, cur, csr, E);

  int gG = (N + 63) / 64;
  mfma_gemm1_k<<<gG, 256, 0, stream>>>(node_x, W1t, dinv, bufC, N);
  gemm2_agg_k<<<gG, 256, 0, stream>>>(bufC, offs, csr, dinv, b1, W2t, bufD, N);
  agg2_pool_k<<<gG, 512, 0, stream>>>(bufD, offs, csr, dinv, b2, nbatch, sums, N);
  head_k<<<B, 512, 0, stream>>>(seq_emb, sums, nbatch, Wf, bfb, Wtp, btp, Wp, bp,
                                (float*)d_out, B, SEQ, N);
}

// Round 14
// 174.623 us; speedup vs baseline: 1.2030x; 1.0007x over previous
//
#include <hip/hip_runtime.h>

// ---------------------------------------------------------------------------
// 2-layer GCN + mean-pool + MLP head.
// R9/R12: agg1 fused into gemm2 A-staging (two-pass 128B slices, unroll x8);
//         pool fused into agg2. R13: head_k parallelized (44us -> ~8us).
// R14: agg2_pool gets the proven x8 unroll tier + 32 nodes/block (256 thr,
//      1563 blocks -> smoother CU balance, 8 blocks/CU).
// ---------------------------------------------------------------------------

#define HID 128

typedef __attribute__((ext_vector_type(8))) short bf16x8;
typedef __attribute__((ext_vector_type(4))) short bf16x4;
typedef __attribute__((ext_vector_type(4))) float f32x4;

static __device__ __forceinline__ short f2bf(float f) {
  union { float f; unsigned u; } v; v.f = f;
  unsigned r = v.u + 0x7fff + ((v.u >> 16) & 1);  // RNE
  return (short)(r >> 16);
}
static __device__ __forceinline__ float bf2f(short s) {
  union { unsigned u; float f; } v;
  v.u = ((unsigned)(unsigned short)s) << 16;
  return v.f;
}

// --- W1/W2 fp32 -> Wt bf16 (transpose + convert) + zero deg (fused) ---
__global__ __launch_bounds__(256) void prep_w_k(const float* __restrict__ W1,
                                                short* __restrict__ W1t,
                                                const float* __restrict__ W2,
                                                short* __restrict__ W2t,
                                                int* __restrict__ deg, int N) {
  int idx = blockIdx.x * 256 + threadIdx.x;
  if (idx < 384 * HID) {
    int k = idx >> 7;
    int c = idx & 127;
    W1t[(size_t)c * 384 + k] = f2bf(W1[idx]);
  } else if (idx < 384 * HID + HID * HID) {
    int j = idx - 384 * HID;
    int k = j >> 7;
    int c = j & 127;
    W2t[(size_t)c * HID + k] = f2bf(W2[j]);
  }
  if (idx < N) deg[idx] = 0;
}

__global__ __launch_bounds__(256) void hist_k(const int* __restrict__ dst,
                                              int* __restrict__ cnt, int E) {
  int i = blockIdx.x * 256 + threadIdx.x;
  if (i < E) atomicAdd(&cnt[dst[i]], 1);
}

// per-256-chunk sums of deg + dinv computation (fused)
__global__ __launch_bounds__(256) void scan_bsum(const int* __restrict__ cnt,
                                                 int* __restrict__ bsum,
                                                 float* __restrict__ dinv, int n) {
  __shared__ int sm[256];
  int i = blockIdx.x * 256 + threadIdx.x;
  int v = (i < n) ? cnt[i] : 0;
  if (i < n) dinv[i] = rsqrtf((float)(v + 1));  // +1 self-loop
  sm[threadIdx.x] = v;
  __syncthreads();
  for (int off = 128; off > 0; off >>= 1) {
    if (threadIdx.x < off) sm[threadIdx.x] += sm[threadIdx.x + off];
    __syncthreads();
  }
  if (threadIdx.x == 0) bsum[blockIdx.x] = sm[0];
}

// offsets: inline exclusive scan of bsum (nb<=256) + per-chunk scan
//          + cur=0 + sums=0 (fused zeroing)
__global__ __launch_bounds__(256) void scan_offsets(const int* __restrict__ cnt,
                                                    const int* __restrict__ bsum,
                                                    int* __restrict__ offs,
                                                    int* __restrict__ cur,
                                                    float* __restrict__ sums,
                                                    int nsum, int n, int nb) {
  __shared__ int sm[256];
  int t = threadIdx.x;
  int bid = blockIdx.x;
  int zi = bid * 256 + t;
  if (zi < nsum) sums[zi] = 0.f;
  // pass 1: inclusive scan of bsum in LDS
  int bv = (t < nb) ? bsum[t] : 0;
  sm[t] = bv;
  __syncthreads();
  for (int off = 1; off < 256; off <<= 1) {
    int add = (t >= off) ? sm[t - off] : 0;
    __syncthreads();
    sm[t] += add;
    __syncthreads();
  }
  int base = (bid > 0) ? sm[bid - 1] : 0;  // exclusive prefix for this block
  __syncthreads();
  // pass 2: scan this block's 256-deg chunk
  int i = bid * 256 + t;
  int v = (i < n) ? cnt[i] : 0;
  sm[t] = v;
  __syncthreads();
  for (int off = 1; off < 256; off <<= 1) {
    int add = (t >= off) ? sm[t - off] : 0;
    __syncthreads();
    sm[t] += add;
    __syncthreads();
  }
  if (i < n) {
    offs[i] = base + sm[t] - v;
    cur[i] = 0;
  }
  if (i == n - 1) offs[n] = base + sm[t];  // total
}

__global__ __launch_bounds__(256) void fill_k(const int* __restrict__ src,
                                              const int* __restrict__ dst,
                                              const int* __restrict__ offs,
                                              int* __restrict__ cur,
                                              int* __restrict__ csr, int E) {
  int i = blockIdx.x * 256 + threadIdx.x;
  if (i >= E) return;
  int d = dst[i];
  int p = offs[d] + atomicAdd(&cur[d], 1);
  csr[p] = src[i];
}

// --- GEMM1: Hs1[M][128] = bf16( (node_x[M][384] @ W1t^T) * dinv[row] ) ---
// 64x128 tile, 4 waves (2x2 of 32x64), BK=64, mfma_f32_16x16x32_bf16.
__global__ __launch_bounds__(256) void mfma_gemm1_k(const float* __restrict__ Af,
                                                    const short* __restrict__ Wt,
                                                    const float* __restrict__ scale,
                                                    short* __restrict__ C, int M) {
  constexpr int K = 384;
  constexpr int BK = 64;
  constexpr int ROWE = BK + 8;  // 72 shorts = 144B rows (16B aligned)
  __shared__ short As[64 * ROWE];
  __shared__ short Bs[128 * ROWE];
  __shared__ float dln[64];

  const int tid = threadIdx.x;
  const int wave = tid >> 6;
  const int lane = tid & 63;
  const int l15 = lane & 15;
  const int lk = lane >> 4;          // k-group 0..3
  const int mh = (wave >> 1) * 32;   // wave row offset in tile
  const int nh = (wave & 1) * 64;    // wave col offset
  const int row0 = blockIdx.x * 64;

  if (tid < 64) {
    int r = row0 + tid;
    dln[tid] = (r < M) ? scale[r] : 0.f;
  }

  f32x4 acc[2][4] = {};

  for (int k0 = 0; k0 < K; k0 += BK) {
    __syncthreads();  // previous iter's LDS reads done before overwrite
#pragma unroll
    for (int it = 0; it < 4; ++it) {
      int f = tid + it * 256;
      int r = f >> 4;
      int kc = (f & 15) << 2;
      int gr = row0 + r;
      float4 v = make_float4(0.f, 0.f, 0.f, 0.f);
      if (gr < M) v = *(const float4*)&Af[(size_t)gr * K + k0 + kc];
      bf16x4 s;
      s[0] = f2bf(v.x); s[1] = f2bf(v.y); s[2] = f2bf(v.z); s[3] = f2bf(v.w);
      *(bf16x4*)&As[r * ROWE + kc] = s;
    }
#pragma unroll
    for (int it = 0; it < 4; ++it) {
      int f = tid + it * 256;
      int r = f >> 3;
      int kc = (f & 7) << 3;
      *(bf16x8*)&Bs[r * ROWE + kc] =
          *(const bf16x8*)&Wt[(size_t)r * K + k0 + kc];
    }
    __syncthreads();
#pragma unroll
    for (int ks = 0; ks < 2; ++ks) {
      bf16x8 af[2], bfr[4];
#pragma unroll
      for (int mf = 0; mf < 2; ++mf)
        af[mf] = *(const bf16x8*)&As[(mh + mf * 16 + l15) * ROWE + ks * 32 + lk * 8];
#pragma unroll
      for (int nf = 0; nf < 4; ++nf)
        bfr[nf] = *(const bf16x8*)&Bs[(nh + nf * 16 + l15) * ROWE + ks * 32 + lk * 8];
#pragma unroll
      for (int mf = 0; mf < 2; ++mf)
#pragma unroll
        for (int nf = 0; nf < 4; ++nf)
          acc[mf][nf] = __builtin_amdgcn_mfma_f32_16x16x32_bf16(
              af[mf], bfr[nf], acc[mf][nf], 0, 0, 0);
    }
  }
  // epilogue: C/D layout col=lane&15, row=(lane>>4)*4+reg
#pragma unroll
  for (int mf = 0; mf < 2; ++mf) {
#pragma unroll
    for (int r = 0; r < 4; ++r) {
      int lr = mh + mf * 16 + lk * 4 + r;
      int gr = row0 + lr;
      if (gr >= M) continue;
      float s = dln[lr];
#pragma unroll
      for (int nf = 0; nf < 4; ++nf)
        C[(size_t)gr * HID + nh + nf * 16 + l15] = f2bf(acc[mf][nf][r] * s);
    }
  }
}

// --- GEMM2 with fused AGG1 A-staging (two-pass, edge unroll x8) ---
__global__ __launch_bounds__(256) void gemm2_agg_k(const short* __restrict__ Hs,
                                                   const int* __restrict__ offs,
                                                   const int* __restrict__ csr,
                                                   const float* __restrict__ dinv,
                                                   const float* __restrict__ b1,
                                                   const short* __restrict__ Wt,
                                                   short* __restrict__ C, int M) {
  constexpr int K = 128;
  constexpr int BK = 64;
  constexpr int ROWE = BK + 8;
  __shared__ short As[64 * ROWE];
  __shared__ short Bs[128 * ROWE];
  __shared__ float dln[64];

  const int tid = threadIdx.x;
  const int wave = tid >> 6;
  const int lane = tid & 63;
  const int l15 = lane & 15;
  const int lk = lane >> 4;
  const int mh = (wave >> 1) * 32;
  const int nh = (wave & 1) * 64;
  const int row0 = blockIdx.x * 64;

  if (tid < 64) {
    int r = row0 + tid;
    dln[tid] = (r < M) ? dinv[r] : 0.f;
  }

  // staging thread mapping: 4 threads per row, 16 cols each
  const int srow = tid >> 2;
  const int sl = tid & 3;
  const int gr = row0 + srow;
  const bool valid = gr < M;
  int es = 0, ee = 0;
  float dvv = 0.f;
  if (valid) {
    es = offs[gr];
    ee = offs[gr + 1];
    dvv = dinv[gr];
  }

  f32x4 acc[2][4] = {};

  for (int k0 = 0; k0 < K; k0 += BK) {
    __syncthreads();
    // stage Wt [128][64]
#pragma unroll
    for (int it = 0; it < 4; ++it) {
      int f = tid + it * 256;
      int r = f >> 3;
      int kc = (f & 7) << 3;
      *(bf16x8*)&Bs[r * ROWE + kc] =
          *(const bf16x8*)&Wt[(size_t)r * K + k0 + kc];
    }
    // stage A via on-the-fly aggregation of cols [k0+sl*16, +16)
    {
      const int cb = k0 + sl * 16;
      float a[16];
#pragma unroll
      for (int q = 0; q < 16; ++q) a[q] = 0.f;
      if (valid) {
        const short* rs = &Hs[(size_t)gr * HID + cb];
        bf16x8 s0 = *(const bf16x8*)rs;
        bf16x8 s1 = *(const bf16x8*)(rs + 8);
#pragma unroll
        for (int q = 0; q < 8; ++q) { a[q] = bf2f(s0[q]); a[8 + q] = bf2f(s1[q]); }
        int p = es;
        for (; p + 8 <= ee; p += 8) {
          int u[8];
#pragma unroll
          for (int q = 0; q < 8; ++q) u[q] = csr[p + q];
          bf16x8 xa[8], xb[8];
#pragma unroll
          for (int q = 0; q < 8; ++q) {
            const short* r0 = &Hs[(size_t)u[q] * HID + cb];
            xa[q] = *(const bf16x8*)r0;
            xb[q] = *(const bf16x8*)(r0 + 8);
          }
#pragma unroll
          for (int q = 0; q < 8; ++q)
#pragma unroll
            for (int r = 0; r < 8; ++r) {
              a[r] += bf2f(xa[q][r]);
              a[8 + r] += bf2f(xb[q][r]);
            }
        }
        for (; p + 4 <= ee; p += 4) {
          int u0 = csr[p + 0];
          int u1 = csr[p + 1];
          int u2 = csr[p + 2];
          int u3 = csr[p + 3];
          const short* r0 = &Hs[(size_t)u0 * HID + cb];
          const short* r1 = &Hs[(size_t)u1 * HID + cb];
          const short* r2 = &Hs[(size_t)u2 * HID + cb];
          const short* r3 = &Hs[(size_t)u3 * HID + cb];
          bf16x8 x0a = *(const bf16x8*)r0, x0b = *(const bf16x8*)(r0 + 8);
          bf16x8 x1a = *(const bf16x8*)r1, x1b = *(const bf16x8*)(r1 + 8);
          bf16x8 x2a = *(const bf16x8*)r2, x2b = *(const bf16x8*)(r2 + 8);
          bf16x8 x3a = *(const bf16x8*)r3, x3b = *(const bf16x8*)(r3 + 8);
#pragma unroll
          for (int q = 0; q < 8; ++q) {
            a[q]     += (bf2f(x0a[q]) + bf2f(x1a[q])) + (bf2f(x2a[q]) + bf2f(x3a[q]));
            a[8 + q] += (bf2f(x0b[q]) + bf2f(x1b[q])) + (bf2f(x2b[q]) + bf2f(x3b[q]));
          }
        }
        for (; p < ee; ++p) {
          int u = csr[p];
          const short* r0 = &Hs[(size_t)u * HID + cb];
          bf16x8 xa = *(const bf16x8*)r0, xb = *(const bf16x8*)(r0 + 8);
#pragma unroll
          for (int q = 0; q < 8; ++q) { a[q] += bf2f(xa[q]); a[8 + q] += bf2f(xb[q]); }
        }
        float4 bb0 = *(const float4*)&b1[cb];
        float4 bb1 = *(const float4*)&b1[cb + 4];
        float4 bb2 = *(const float4*)&b1[cb + 8];
        float4 bb3 = *(const float4*)&b1[cb + 12];
        float bbv[16] = {bb0.x, bb0.y, bb0.z, bb0.w, bb1.x, bb1.y, bb1.z, bb1.w,
                         bb2.x, bb2.y, bb2.z, bb2.w, bb3.x, bb3.y, bb3.z, bb3.w};
#pragma unroll
        for (int q = 0; q < 16; ++q)
          a[q] = fmaxf(fmaf(a[q], dvv, bbv[q]), 0.f);
      }
      bf16x8 o0, o1;
#pragma unroll
      for (int q = 0; q < 8; ++q) { o0[q] = f2bf(a[q]); o1[q] = f2bf(a[8 + q]); }
      *(bf16x8*)&As[srow * ROWE + sl * 16] = o0;
      *(bf16x8*)&As[srow * ROWE + sl * 16 + 8] = o1;
    }
    __syncthreads();
#pragma unroll
    for (int ks = 0; ks < 2; ++ks) {
      bf16x8 af[2], bfr[4];
#pragma unroll
      for (int mf = 0; mf < 2; ++mf)
        af[mf] = *(const bf16x8*)&As[(mh + mf * 16 + l15) * ROWE + ks * 32 + lk * 8];
#pragma unroll
      for (int nf = 0; nf < 4; ++nf)
        bfr[nf] = *(const bf16x8*)&Bs[(nh + nf * 16 + l15) * ROWE + ks * 32 + lk * 8];
#pragma unroll
      for (int mf = 0; mf < 2; ++mf)
#pragma unroll
        for (int nf = 0; nf < 4; ++nf)
          acc[mf][nf] = __builtin_amdgcn_mfma_f32_16x16x32_bf16(
              af[mf], bfr[nf], acc[mf][nf], 0, 0, 0);
    }
  }
#pragma unroll
  for (int mf = 0; mf < 2; ++mf) {
#pragma unroll
    for (int r = 0; r < 4; ++r) {
      int lr = mh + mf * 16 + lk * 4 + r;
      int g2 = row0 + lr;
      if (g2 >= M) continue;
      float s = dln[lr];
#pragma unroll
      for (int nf = 0; nf < 4; ++nf)
        C[(size_t)g2 * HID + nh + nf * 16 + l15] = f2bf(acc[mf][nf][r] * s);
    }
  }
}

// --- AGG2 + mean-pool stage 1 (fused; no Hs2 writeback):
//   g2[v] = relu(dinv[v]*(Hs2[v] + sum_in Hs2[u]) + b2); sums[batch[v]] += g2[v]
// R14: 256 threads, 32 nodes/block (1563 blocks, 8 blocks/CU), 8 lanes/node
//      x 16 cols, edge unroll x8/x4/x1.
__global__ __launch_bounds__(256) void agg2_pool_k(const short* __restrict__ Hs,
                                                   const int* __restrict__ offs,
                                                   const int* __restrict__ csr,
                                                   const float* __restrict__ dinv,
                                                   const float* __restrict__ b2,
                                                   const int* __restrict__ batch,
                                                   float* __restrict__ sums,
                                                   int N) {
  const int nid = threadIdx.x >> 3;   // 0..31
  const int l8 = threadIdx.x & 7;     // owns 16 cols
  const int v = blockIdx.x * 32 + nid;
  const int cb = l8 * 16;
  float a[16];
#pragma unroll
  for (int q = 0; q < 16; ++q) a[q] = 0.f;
  const bool valid = v < N;
  if (valid) {
    int es = offs[v];
    int ee = offs[v + 1];
    const short* rs = &Hs[(size_t)v * HID + cb];
    bf16x8 s0 = *(const bf16x8*)rs;
    bf16x8 s1 = *(const bf16x8*)(rs + 8);
#pragma unroll
    for (int q = 0; q < 8; ++q) { a[q] = bf2f(s0[q]); a[8 + q] = bf2f(s1[q]); }
    int p = es;
    for (; p + 8 <= ee; p += 8) {
      int u[8];
#pragma unroll
      for (int q = 0; q < 8; ++q) u[q] = csr[p + q];
      bf16x8 xa[8], xb[8];
#pragma unroll
      for (int q = 0; q < 8; ++q) {
        const short* r0 = &Hs[(size_t)u[q] * HID + cb];
        xa[q] = *(const bf16x8*)r0;
        xb[q] = *(const bf16x8*)(r0 + 8);
      }
#pragma unroll
      for (int q = 0; q < 8; ++q)
#pragma unroll
        for (int r = 0; r < 8; ++r) {
          a[r] += bf2f(xa[q][r]);
          a[8 + r] += bf2f(xb[q][r]);
        }
    }
    for (; p + 4 <= ee; p += 4) {
      int u0 = csr[p + 0];
      int u1 = csr[p + 1];
      int u2 = csr[p + 2];
      int u3 = csr[p + 3];
      const short* r0 = &Hs[(size_t)u0 * HID + cb];
      const short* r1 = &Hs[(size_t)u1 * HID + cb];
      const short* r2 = &Hs[(size_t)u2 * HID + cb];
      const short* r3 = &Hs[(size_t)u3 * HID + cb];
      bf16x8 x0a = *(const bf16x8*)r0, x0b = *(const bf16x8*)(r0 + 8);
      bf16x8 x1a = *(const bf16x8*)r1, x1b = *(const bf16x8*)(r1 + 8);
      bf16x8 x2a = *(const bf16x8*)r2, x2b = *(const bf16x8*)(r2 + 8);
      bf16x8 x3a = *(const bf16x8*)r3, x3b = *(const bf16x8*)(r3 + 8);
#pragma unroll
      for (int q = 0; q < 8; ++q) {
        a[q]     += (bf2f(x0a[q]) + bf2f(x1a[q])) + (bf2f(x2a[q]) + bf2f(x3a[q]));
        a[8 + q] += (bf2f(x0b[q]) + bf2f(x1b[q])) + (bf2f(x2b[q]) + bf2f(x3b[q]));
      }
    }
    for (; p < ee; ++p) {
      int u = csr[p];
      const short* r0 = &Hs[(size_t)u * HID + cb];
      bf16x8 xa = *(const bf16x8*)r0, xb = *(const bf16x8*)(r0 + 8);
#pragma unroll
      for (int q = 0; q < 8; ++q) { a[q] += bf2f(xa[q]); a[8 + q] += bf2f(xb[q]); }
    }
    float dv = dinv[v];
    float4 bb0 = *(const float4*)&b2[cb];
    float4 bb1 = *(const float4*)&b2[cb + 4];
    float4 bb2v = *(const float4*)&b2[cb + 8];
    float4 bb3 = *(const float4*)&b2[cb + 12];
    float bbv[16] = {bb0.x, bb0.y, bb0.z, bb0.w, bb1.x, bb1.y, bb1.z, bb1.w,
                     bb2v.x, bb2v.y, bb2v.z, bb2v.w, bb3.x, bb3.y, bb3.z, bb3.w};
#pragma unroll
    for (int q = 0; q < 16; ++q)
      a[q] = fmaxf(fmaf(a[q], dv, bbv[q]), 0.f);
  }
  // pool: segmented LDS reduce over sorted batch -> atomicAdd into sums
  __shared__ float ot[32 * 133];  // stride 133 floats to spread banks
  __shared__ int bsm[32];
#pragma unroll
  for (int q = 0; q < 16; ++q) ot[nid * 133 + cb + q] = a[q];
  if (threadIdx.x < 32) {
    int vv = blockIdx.x * 32 + threadIdx.x;
    bsm[threadIdx.x] = batch[vv < N ? vv : N - 1];  // invalid rows carry a=0
  }
  __syncthreads();
  int j = threadIdx.x & 127;  // column
  int h = threadIdx.x >> 7;   // 2 groups of 16 rows
  int r0 = h * 16;
  int g_cur = bsm[r0];
  float acc = 0.f;
#pragma unroll
  for (int rr = r0; rr < r0 + 16; ++rr) {
    int g = bsm[rr];
    if (g != g_cur) {
      atomicAdd(&sums[(size_t)g_cur * HID + j], acc);
      acc = 0.f;
      g_cur = g;
    }
    acc += ot[rr * 133 + j];
  }
  atomicAdd(&sums[(size_t)g_cur * HID + j], acc);
}

// --- head (R13): 512 threads, 4-way k-split + LDS reduce + shuffle tail ---
__global__ __launch_bounds__(512) void head_k(const float* __restrict__ seq,
                                              const float* __restrict__ sums,
                                              const int* __restrict__ batch,
                                              const float* __restrict__ Wf,
                                              const float* __restrict__ bf,
                                              const float* __restrict__ Wtp,
                                              const float* __restrict__ btp,
                                              const float* __restrict__ Wp,
                                              const float* __restrict__ bp,
                                              float* __restrict__ outp,
                                              int B, int SEQ, int n) {
  int g = blockIdx.x;
  int t = threadIdx.x;
  __shared__ float xin[512];
  __shared__ float ps[4][128];
  __shared__ float fs[128];
  // per-graph node count via binary search over sorted batch (all threads)
  int lo = 0, hi = n;
  while (lo < hi) { int mid = (lo + hi) >> 1; if (batch[mid] < g) lo = mid + 1; else hi = mid; }
  int start = lo;
  hi = n;
  while (lo < hi) { int mid = (lo + hi) >> 1; if (batch[mid] <= g) lo = mid + 1; else hi = mid; }
  float inv_cnt = 1.f / fmaxf((float)(lo - start), 1.f);
  // stage xin: [seq(384) | pooled(128)]
  if (t < SEQ) xin[t] = seq[(size_t)g * SEQ + t];
  else xin[t] = sums[g * HID + (t - SEQ)] * inv_cnt;
  __syncthreads();
  // partial dot: thread (j = t&127, ks = t>>7) sums 128 k's
  int j = t & 127;
  int ks = t >> 7;
  int kb = ks * 128;
  float acc = 0.f;
#pragma unroll 8
  for (int k = 0; k < 128; ++k)
    acc = fmaf(xin[kb + k], Wf[(size_t)(kb + k) * HID + j], acc);
  ps[ks][j] = acc;
  __syncthreads();
  if (t < 128) {
    float s = ps[0][t] + ps[1][t] + ps[2][t] + ps[3][t] + bf[t];
    fs[t] = fmaxf(s, 0.f);
  }
  __syncthreads();
  // tail: wave 0 reduces the three tiny dots via shuffle butterfly
  if (t < 64) {
    float f0 = fs[t], f1 = fs[t + 64];
    float p0 = f0 * Wtp[t * 2]     + f1 * Wtp[(t + 64) * 2];
    float p1 = f0 * Wtp[t * 2 + 1] + f1 * Wtp[(t + 64) * 2 + 1];
    float p2 = f0 * Wp[t]          + f1 * Wp[t + 64];
#pragma unroll
    for (int off = 32; off > 0; off >>= 1) {
      p0 += __shfl_xor(p0, off);
      p1 += __shfl_xor(p1, off);
      p2 += __shfl_xor(p2, off);
    }
    if (t == 0) {
      outp[g * 2 + 0] = p0 + btp[0];
      outp[g * 2 + 1] = p1 + btp[1];
      outp[B * 2 + g] = p2 + bp[0];
    }
  }
}

extern "C" void kernel_launch(void* const* d_in, const int* in_sizes, int n_in,
                              void* d_out, int out_size, void* d_ws, size_t ws_size,
                              hipStream_t stream) {
  const float* seq_emb = (const float*)d_in[0];
  const float* node_x  = (const float*)d_in[1];
  const int*   eidx    = (const int*)d_in[2];
  const int*   nbatch  = (const int*)d_in[3];
  const float* W1  = (const float*)d_in[4];
  const float* b1  = (const float*)d_in[5];
  const float* W2  = (const float*)d_in[6];
  const float* b2  = (const float*)d_in[7];
  const float* Wf  = (const float*)d_in[8];
  const float* bfb = (const float*)d_in[9];
  const float* Wtp = (const float*)d_in[10];
  const float* btp = (const float*)d_in[11];
  const float* Wp  = (const float*)d_in[12];
  const float* bp  = (const float*)d_in[13];

  const int N = in_sizes[3];           // 50000 nodes
  const int E = in_sizes[2] / 2;       // 600000 edges
  const int SEQ = 384;
  const int B = in_sizes[0] / SEQ;     // 64 graphs

  char* w = (char*)d_ws;
  auto alloc = [&](size_t bytes) -> void* {
    void* p = (void*)w;
    w += (bytes + 255) & ~(size_t)255;
    return p;
  };
  float* dinv   = (float*)alloc((size_t)N * 4);
  int*   deg    = (int*)alloc((size_t)N * 4);
  int*   cur    = (int*)alloc((size_t)N * 4);
  int*   offs   = (int*)alloc((size_t)(N + 1) * 4);
  int*   bsum   = (int*)alloc(1024);
  int*   csr    = (int*)alloc((size_t)E * 4);
  short* W1t    = (short*)alloc((size_t)SEQ * HID * 2);
  short* W2t    = (short*)alloc((size_t)HID * HID * 2);
  short* bufC   = (short*)alloc((size_t)N * HID * 2);   // Hs1 bf16
  short* bufD   = (short*)alloc((size_t)N * HID * 2);   // Hs2 bf16
  float* sums   = (float*)alloc((size_t)B * HID * 4);

  const int* srcp = eidx;
  const int* dstp = eidx + E;

  int gE = (E + 255) / 256;
  int gN = (N + 255) / 256;  // 196 <= 256 (required by inline bsum scan)
  int wElems = SEQ * HID + HID * HID;
  int gP = (max(wElems, N) + 255) / 256;

  prep_w_k<<<gP, 256, 0, stream>>>(W1, W1t, W2, W2t, deg, N);
  hist_k<<<gE, 256, 0, stream>>>(dstp, deg, E);
  scan_bsum<<<gN, 256, 0, stream>>>(deg, bsum, dinv, N);
  scan_offsets<<<gN, 256, 0, stream>>>(deg, bsum, offs, cur, sums, B * HID, N, gN);
  fill_k<<<gE, 256, 0, stream>>>(srcp, dstp, offs, cur, csr, E);

  int gG = (N + 63) / 64;
  int gA2 = (N + 31) / 32;
  mfma_gemm1_k<<<gG, 256, 0, stream>>>(node_x, W1t, dinv, bufC, N);
  gemm2_agg_k<<<gG, 256, 0, stream>>>(bufC, offs, csr, dinv, b1, W2t, bufD, N);
  agg2_pool_k<<<gA2, 256, 0, stream>>>(bufD, offs, csr, dinv, b2, nbatch, sums, N);
  head_k<<<B, 512, 0, stream>>>(seq_emb, sums, nbatch, Wf, bfb, Wtp, btp, Wp, bp,
                                (float*)d_out, B, SEQ, N);
}